// Round 1
// baseline (859.302 us; speedup 1.0000x reference)
//
#include <hip/hip_runtime.h>
#include <hip/hip_bf16.h>
#include <math.h>

// Problem constants
#define BB 2
#define CC 192
#define SS 16
#define HH 32
#define WW 32
#define NH 6
#define PP 4
#define HD 32
#define HID 768
#define LL (SS * HH * WW)        // 16384
#define MTOK (BB * LL)           // 32768 tokens
#define NPROJ 288                // 192 (value) + 72 (off) + 24 (aw)

// ---------------------------------------------------------------------------
// Build concatenated projection weight [C x 288] and bias [288]
// cols 0..191 = Wv, 192..263 = Woff, 264..287 = Waw
// ---------------------------------------------------------------------------
__global__ void build_wcat(const float* __restrict__ Wv, const float* __restrict__ Woff,
                           const float* __restrict__ Waw, const float* __restrict__ bv,
                           const float* __restrict__ boff, const float* __restrict__ baw,
                           float* __restrict__ Wcat, float* __restrict__ bcat) {
    int i = blockIdx.x * 256 + threadIdx.x;
    if (i < CC * NPROJ) {
        int r = i / NPROJ, c = i % NPROJ;
        float v;
        if (c < 192)      v = Wv[r * 192 + c];
        else if (c < 264) v = Woff[r * 72 + (c - 192)];
        else              v = Waw[r * 24 + (c - 264)];
        Wcat[i] = v;
    } else if (i < CC * NPROJ + NPROJ) {
        int c = i - CC * NPROJ;
        float v;
        if (c < 192)      v = bv[c];
        else if (c < 264) v = boff[c - 192];
        else              v = baw[c - 264];
        bcat[c] = v;
    }
}

// ---------------------------------------------------------------------------
// x (B, C, L) channel-major  ->  xp (B, L, C) token-major   (tiled transpose)
// ---------------------------------------------------------------------------
__global__ void transpose_in(const float* __restrict__ x, float* __restrict__ xp) {
    __shared__ float s[32][33];
    int b = blockIdx.z;
    int c0 = blockIdx.y * 32;   // C/32 = 6 tiles
    int l0 = blockIdx.x * 32;   // L/32 = 512 tiles
    int tx = threadIdx.x, ty = threadIdx.y;
#pragma unroll
    for (int r = 0; r < 32; r += 8)
        s[ty + r][tx] = x[((size_t)b * CC + c0 + ty + r) * LL + l0 + tx];
    __syncthreads();
#pragma unroll
    for (int r = 0; r < 32; r += 8)
        xp[((size_t)b * LL + l0 + ty + r) * CC + c0 + tx] = s[tx][ty + r];
}

// ---------------------------------------------------------------------------
// h2 (B, L, C) -> out (B, C, L)
// ---------------------------------------------------------------------------
__global__ void transpose_out(const float* __restrict__ h2, float* __restrict__ out) {
    __shared__ float s[32][33];
    int b = blockIdx.z;
    int c0 = blockIdx.y * 32;
    int l0 = blockIdx.x * 32;
    int tx = threadIdx.x, ty = threadIdx.y;
#pragma unroll
    for (int r = 0; r < 32; r += 8)
        s[ty + r][tx] = h2[((size_t)b * LL + l0 + ty + r) * CC + c0 + tx];
    __syncthreads();
#pragma unroll
    for (int r = 0; r < 32; r += 8)
        out[((size_t)b * CC + c0 + ty + r) * LL + l0 + tx] = s[tx][ty + r];
}

// ---------------------------------------------------------------------------
// Tiled fp32 GEMM:  Cm = A(MxK) @ Bw(KxN) + bias[n] (+ add[m,n] if add != null)
// BM=64 BN=64 BK=16, 256 threads, 4x4 micro-tile. M % 64 == 0, K % 16 == 0.
// ---------------------------------------------------------------------------
#define GBM 64
#define GBN 64
#define GBK 16
__global__ __launch_bounds__(256) void gemm_bias(const float* __restrict__ A,
                                                 const float* __restrict__ Bw,
                                                 const float* __restrict__ bias,
                                                 const float* __restrict__ add,
                                                 float* __restrict__ Cm,
                                                 int M, int N, int K) {
    __shared__ float As[GBK][GBM + 1];
    __shared__ float Bs[GBK][GBN + 1];
    int t = threadIdx.x;
    int m0 = blockIdx.y * GBM;
    int n0 = blockIdx.x * GBN;
    int tm = t >> 4, tn = t & 15;            // 16x16 thread grid, 4x4 each
    int arow = t >> 2;                       // 0..63
    int akk = (t & 3) * 4;                   // 0,4,8,12
    int brow = t >> 6;                       // 0..3
    int bcol = t & 63;
    float acc[4][4] = {{0.f}};

    for (int k0 = 0; k0 < K; k0 += GBK) {
        float4 av = *reinterpret_cast<const float4*>(A + (size_t)(m0 + arow) * K + k0 + akk);
        As[akk + 0][arow] = av.x;
        As[akk + 1][arow] = av.y;
        As[akk + 2][arow] = av.z;
        As[akk + 3][arow] = av.w;
#pragma unroll
        for (int i = 0; i < 4; ++i) {
            int kk = brow + i * 4;
            float bvv = 0.f;
            if (n0 + bcol < N) bvv = Bw[(size_t)(k0 + kk) * N + n0 + bcol];
            Bs[kk][bcol] = bvv;
        }
        __syncthreads();
#pragma unroll
        for (int kk = 0; kk < GBK; ++kk) {
            float a[4], bq[4];
#pragma unroll
            for (int i = 0; i < 4; ++i) a[i] = As[kk][tm * 4 + i];
#pragma unroll
            for (int j = 0; j < 4; ++j) bq[j] = Bs[kk][tn * 4 + j];
#pragma unroll
            for (int i = 0; i < 4; ++i)
#pragma unroll
                for (int j = 0; j < 4; ++j) acc[i][j] += a[i] * bq[j];
        }
        __syncthreads();
    }
#pragma unroll
    for (int i = 0; i < 4; ++i) {
        int m = m0 + tm * 4 + i;
#pragma unroll
        for (int j = 0; j < 4; ++j) {
            int n = n0 + tn * 4 + j;
            if (n < N) {
                float v = acc[i][j] + bias[n];
                if (add) v += add[(size_t)m * N + n];
                Cm[(size_t)m * N + n] = v;
            }
        }
    }
}

// ---------------------------------------------------------------------------
// Deformable sampling. proj rows: [value(192) | off(72) | aw_logits(24)]
// One 32-lane group per (b, l, head); lane = channel within head.
// ---------------------------------------------------------------------------
__global__ __launch_bounds__(256) void deform_kernel(const float* __restrict__ proj,
                                                     float* __restrict__ dout) {
    int g = blockIdx.x * 8 + (threadIdx.x >> 5);   // group id over B*L*NH
    int lane = threadIdx.x & 31;
    int h = g % NH;
    int tmp = g / NH;
    int l = tmp % LL;
    int b = tmp / LL;

    int d = l >> 10;            // l / (H*W)
    int rem = l & 1023;
    int y = rem >> 5;
    int xw = rem & 31;

    const float* rowp = proj + (size_t)(b * LL + l) * NPROJ;

    // attention-weight softmax over P=4
    float lg0 = rowp[264 + h * 4 + 0];
    float lg1 = rowp[264 + h * 4 + 1];
    float lg2 = rowp[264 + h * 4 + 2];
    float lg3 = rowp[264 + h * 4 + 3];
    float mx = fmaxf(fmaxf(lg0, lg1), fmaxf(lg2, lg3));
    float e0 = __expf(lg0 - mx), e1 = __expf(lg1 - mx);
    float e2 = __expf(lg2 - mx), e3 = __expf(lg3 - mx);
    float inv = 1.0f / (e0 + e1 + e2 + e3);
    float awv[4] = {e0 * inv, e1 * inv, e2 * inv, e3 * inv};

    const float* vbase = proj + (size_t)b * LL * NPROJ + h * HD + lane;
    float acc = 0.f;
#pragma unroll
    for (int p = 0; p < PP; ++p) {
        float od = rowp[192 + (h * PP + p) * 3 + 0];
        float ox = rowp[192 + (h * PP + p) * 3 + 1];
        float oy = rowp[192 + (h * PP + p) * 3 + 2];
        float locd = (d + 0.5f) / SS + od / SS;
        float locx = (xw + 0.5f) / WW + ox / WW;
        float locy = (y + 0.5f) / HH + oy / HH;
        float pd = locd * SS - 0.5f;
        float px = locx * WW - 0.5f;
        float py = locy * HH - 0.5f;
        float d0f = floorf(pd), x0f = floorf(px), y0f = floorf(py);
        float fd = pd - d0f, fx = px - x0f, fy = py - y0f;
        int d0 = (int)d0f, x0 = (int)x0f, y0 = (int)y0f;
        float awp = awv[p];
#pragma unroll
        for (int dd = 0; dd < 2; ++dd) {
#pragma unroll
            for (int dy = 0; dy < 2; ++dy) {
#pragma unroll
                for (int dx = 0; dx < 2; ++dx) {
                    int di = d0 + dd, yi = y0 + dy, xi = x0 + dx;
                    bool inb = (di >= 0) & (di < SS) & (yi >= 0) & (yi < HH) &
                               (xi >= 0) & (xi < WW);
                    if (inb) {
                        float wgt = (dd ? fd : 1.f - fd) * (dy ? fy : 1.f - fy) *
                                    (dx ? fx : 1.f - fx);
                        int idx = (di * HH + yi) * WW + xi;
                        acc += awp * wgt * vbase[(size_t)idx * NPROJ];
                    }
                }
            }
        }
    }
    dout[(size_t)(b * LL + l) * CC + h * HD + lane] = acc;
}

// ---------------------------------------------------------------------------
// LayerNorm over C=192, one wave (64 lanes) per row; 4 rows per block.
// ---------------------------------------------------------------------------
__global__ __launch_bounds__(256) void layernorm_kernel(const float* __restrict__ hin,
                                                        const float* __restrict__ g2,
                                                        const float* __restrict__ b2,
                                                        float* __restrict__ lnout) {
    int row = blockIdx.x * 4 + (threadIdx.x >> 6);
    int lane = threadIdx.x & 63;
    const float* hr = hin + (size_t)row * CC;
    float v0 = hr[lane], v1 = hr[lane + 64], v2 = hr[lane + 128];
    float s = v0 + v1 + v2;
    float sq = v0 * v0 + v1 * v1 + v2 * v2;
#pragma unroll
    for (int o = 32; o > 0; o >>= 1) {
        s += __shfl_xor(s, o);
        sq += __shfl_xor(sq, o);
    }
    float m = s * (1.0f / CC);
    float var = sq * (1.0f / CC) - m * m;
    float r = rsqrtf(var + 1e-5f);
    float* lo = lnout + (size_t)row * CC;
    lo[lane]       = (v0 - m) * r * g2[lane]       + b2[lane];
    lo[lane + 64]  = (v1 - m) * r * g2[lane + 64]  + b2[lane + 64];
    lo[lane + 128] = (v2 - m) * r * g2[lane + 128] + b2[lane + 128];
}

// ---------------------------------------------------------------------------
// Fused MLP: out = h + gelu(ln @ W1 + b1) @ W2 + b2m
// 32 tokens per block; hidden processed in chunks of 64 staged in LDS.
// ---------------------------------------------------------------------------
__global__ __launch_bounds__(256) void mlp_kernel(const float* __restrict__ ln,
                                                  const float* __restrict__ hres,
                                                  const float* __restrict__ W1,
                                                  const float* __restrict__ b1,
                                                  const float* __restrict__ W2,
                                                  const float* __restrict__ b2m,
                                                  float* __restrict__ out) {
    __shared__ float ln_s[32][200];
    __shared__ float hid_s[32][72];
    int t = threadIdx.x;
    size_t row0 = (size_t)blockIdx.x * 32;

    for (int i = t; i < 32 * CC; i += 256) {
        int m = i / CC, c = i % CC;
        ln_s[m][c] = ln[(row0 + m) * CC + c];
    }
    __syncthreads();

    int n = t & 63;            // hidden col within chunk (phase A); also cg (phase B)
    int mrow = (t >> 6) * 8;   // 8 token rows for this thread

    float acc[8][3];
#pragma unroll
    for (int i = 0; i < 8; ++i)
#pragma unroll
        for (int q = 0; q < 3; ++q) acc[i][q] = 0.f;

    for (int j = 0; j < HID; j += 64) {
        // ---- phase A: hidden = gelu(ln @ W1 + b1) for cols [j, j+64)
        float ha[8];
        float bb = b1[j + n];
#pragma unroll
        for (int i = 0; i < 8; ++i) ha[i] = bb;
        for (int k = 0; k < CC; k += 4) {
            float w0 = W1[(size_t)(k + 0) * HID + j + n];
            float w1 = W1[(size_t)(k + 1) * HID + j + n];
            float w2 = W1[(size_t)(k + 2) * HID + j + n];
            float w3 = W1[(size_t)(k + 3) * HID + j + n];
#pragma unroll
            for (int i = 0; i < 8; ++i) {
                float4 lv = *reinterpret_cast<const float4*>(&ln_s[mrow + i][k]);
                ha[i] += lv.x * w0 + lv.y * w1 + lv.z * w2 + lv.w * w3;
            }
        }
        __syncthreads();   // previous phase-B readers done
#pragma unroll
        for (int i = 0; i < 8; ++i) {
            float hv = ha[i];
            hid_s[mrow + i][n] = 0.5f * hv * (1.0f + erff(hv * 0.70710678118654752f));
        }
        __syncthreads();
        // ---- phase B: acc += hidden @ W2[j:j+64, :]
        for (int nn = 0; nn < 64; ++nn) {
            float w2a = W2[(size_t)(j + nn) * CC + n];
            float w2b = W2[(size_t)(j + nn) * CC + n + 64];
            float w2c = W2[(size_t)(j + nn) * CC + n + 128];
#pragma unroll
            for (int i = 0; i < 8; ++i) {
                float hv = hid_s[mrow + i][nn];
                acc[i][0] += hv * w2a;
                acc[i][1] += hv * w2b;
                acc[i][2] += hv * w2c;
            }
        }
    }
#pragma unroll
    for (int i = 0; i < 8; ++i) {
        size_t r = row0 + mrow + i;
#pragma unroll
        for (int q = 0; q < 3; ++q) {
            int c = n + q * 64;
            out[r * CC + c] = hres[r * CC + c] + acc[i][q] + b2m[c];
        }
    }
}

// ---------------------------------------------------------------------------
extern "C" void kernel_launch(void* const* d_in, const int* in_sizes, int n_in,
                              void* d_out, int out_size, void* d_ws, size_t ws_size,
                              hipStream_t stream) {
    const float* x    = (const float*)d_in[0];
    // d_in[1] = mask_matrix (unused)
    const float* Wv   = (const float*)d_in[2];
    const float* bv   = (const float*)d_in[3];
    const float* Woff = (const float*)d_in[4];
    const float* boff = (const float*)d_in[5];
    const float* Waw  = (const float*)d_in[6];
    const float* baw  = (const float*)d_in[7];
    const float* Wout = (const float*)d_in[8];
    const float* bout = (const float*)d_in[9];
    const float* g2   = (const float*)d_in[10];
    const float* b2   = (const float*)d_in[11];
    const float* W1   = (const float*)d_in[12];
    const float* b1   = (const float*)d_in[13];
    const float* W2   = (const float*)d_in[14];
    const float* b2m  = (const float*)d_in[15];

    float* ws   = (float*)d_ws;
    float* proj = ws;                    // 32768*288 = 9,437,184
    float* xp   = ws + 9437184;          // 6,291,456
    float* dbuf = ws + 15728640;         // 6,291,456  (deform out, then final h2)
    float* hbuf = ws + 22020096;         // 6,291,456
    float* wcat = ws + 28311552;         // 55,296
    float* bcat = ws + 28366848;         // 288
    float* out  = (float*)d_out;

    build_wcat<<<(CC * NPROJ + NPROJ + 255) / 256, 256, 0, stream>>>(
        Wv, Woff, Waw, bv, boff, baw, wcat, bcat);
    transpose_in<<<dim3(LL / 32, CC / 32, BB), dim3(32, 8), 0, stream>>>(x, xp);
    gemm_bias<<<dim3((NPROJ + GBN - 1) / GBN, MTOK / GBM), 256, 0, stream>>>(
        xp, wcat, bcat, nullptr, proj, MTOK, NPROJ, CC);
    deform_kernel<<<(BB * LL * NH) / 8, 256, 0, stream>>>(proj, dbuf);
    gemm_bias<<<dim3(CC / GBN, MTOK / GBM), 256, 0, stream>>>(
        dbuf, Wout, bout, x /* shortcut view */, hbuf, MTOK, CC, CC);
    layernorm_kernel<<<MTOK / 4, 256, 0, stream>>>(hbuf, g2, b2, xp);
    mlp_kernel<<<MTOK / 32, 256, 0, stream>>>(xp, hbuf, W1, b1, W2, b2m, dbuf);
    transpose_out<<<dim3(LL / 32, CC / 32, BB), dim3(32, 8), 0, stream>>>(dbuf, out);
}

// Round 3
// 352.047 us; speedup vs baseline: 2.4409x; 2.4409x over previous
//
#include <hip/hip_runtime.h>
#include <hip/hip_bf16.h>
#include <math.h>

// Problem constants
#define BB 2
#define CC 192
#define SS 16
#define HH 32
#define WW 32
#define NH 6
#define PP 4
#define HD 32
#define HID 768
#define LL (SS * HH * WW)        // 16384
#define MTOK (BB * LL)           // 32768 tokens
#define NPROJ 288                // 192 (value) + 72 (off) + 24 (aw)

typedef unsigned short u16;
typedef u16 u16x8 __attribute__((ext_vector_type(8)));
typedef __bf16 bf16x8 __attribute__((ext_vector_type(8)));
typedef float f32x4 __attribute__((ext_vector_type(4)));

static __device__ __forceinline__ u16 f2b(float f) {
    __hip_bfloat16 h = __float2bfloat16(f);
    return *reinterpret_cast<u16*>(&h);
}

// ---------------------------------------------------------------------------
// Build all bf16 transposed weights (N x K layout) + concatenated bias (fp32)
// ---------------------------------------------------------------------------
__global__ void build_weights(const float* __restrict__ Wv, const float* __restrict__ Woff,
                              const float* __restrict__ Waw, const float* __restrict__ Wout,
                              const float* __restrict__ W1, const float* __restrict__ W2,
                              const float* __restrict__ bv, const float* __restrict__ boff,
                              const float* __restrict__ baw,
                              u16* __restrict__ wcatT, u16* __restrict__ woutT,
                              u16* __restrict__ w1T, u16* __restrict__ w2T,
                              float* __restrict__ bcat) {
    int i = blockIdx.x * 256 + threadIdx.x;
    if (i < NPROJ * CC) {                       // wcatT[n][k] = Wcat[k][n]
        int n = i / CC, k = i % CC;
        float v = (n < 192) ? Wv[k * 192 + n]
                : (n < 264) ? Woff[k * 72 + (n - 192)]
                            : Waw[k * 24 + (n - 264)];
        wcatT[i] = f2b(v);
        return;
    }
    i -= NPROJ * CC;
    if (i < CC * CC) {                          // woutT[n][k] = Wout[k][n]
        int n = i / CC, k = i % CC;
        woutT[i] = f2b(Wout[k * CC + n]);
        return;
    }
    i -= CC * CC;
    if (i < HID * CC) {                         // w1T[n][k] = W1[k][n]
        int n = i / CC, k = i % CC;
        w1T[i] = f2b(W1[k * HID + n]);
        return;
    }
    i -= HID * CC;
    if (i < CC * HID) {                         // w2T[n][k] = W2[k][n]
        int n = i / HID, k = i % HID;
        w2T[i] = f2b(W2[k * CC + n]);
        return;
    }
    i -= CC * HID;
    if (i < NPROJ) {
        float v = (i < 192) ? bv[i] : (i < 264) ? boff[i - 192] : baw[i - 264];
        bcat[i] = v;
    }
}

// ---------------------------------------------------------------------------
// x (B, C, L) channel-major  ->  xp (B, L, C) token-major bf16
// ---------------------------------------------------------------------------
__global__ void transpose_in(const float* __restrict__ x, u16* __restrict__ xp) {
    __shared__ float s[32][33];
    int b = blockIdx.z;
    int c0 = blockIdx.y * 32;
    int l0 = blockIdx.x * 32;
    int tx = threadIdx.x, ty = threadIdx.y;
#pragma unroll
    for (int r = 0; r < 32; r += 8)
        s[ty + r][tx] = x[((size_t)b * CC + c0 + ty + r) * LL + l0 + tx];
    __syncthreads();
#pragma unroll
    for (int r = 0; r < 32; r += 8)
        xp[((size_t)b * LL + l0 + ty + r) * CC + c0 + tx] = f2b(s[tx][ty + r]);
}

// ---------------------------------------------------------------------------
// h2 (B, L, C) fp32 -> out (B, C, L) fp32
// ---------------------------------------------------------------------------
__global__ void transpose_out(const float* __restrict__ h2, float* __restrict__ out) {
    __shared__ float s[32][33];
    int b = blockIdx.z;
    int c0 = blockIdx.y * 32;
    int l0 = blockIdx.x * 32;
    int tx = threadIdx.x, ty = threadIdx.y;
#pragma unroll
    for (int r = 0; r < 32; r += 8)
        s[ty + r][tx] = h2[((size_t)b * LL + l0 + ty + r) * CC + c0 + tx];
    __syncthreads();
#pragma unroll
    for (int r = 0; r < 32; r += 8)
        out[((size_t)b * CC + c0 + ty + r) * LL + l0 + tx] = s[tx][ty + r];
}

// ---------------------------------------------------------------------------
// MFMA bf16 GEMM: C(MxN) = A(MxK) @ Bt(NxK)^T + bias (+ add) [+ gelu]
// BM=64, BN=96, BK=32. 256 threads = 4 waves (2x2), each wave 32x48.
// EPI: 0 = fp32 out + bias            (proj)
//      1 = fp32 out + bias + add      (wout + shortcut)
//      2 = bf16 out gelu(acc + bias)  (fc1)
//      3 = fp32 out + bias + add      (fc2 + residual)
// ---------------------------------------------------------------------------
template<int EPI>
__global__ __launch_bounds__(256) void gemm_mfma(const u16* __restrict__ A,
                                                 const u16* __restrict__ Bt,
                                                 const float* __restrict__ bias,
                                                 const float* __restrict__ add,
                                                 void* __restrict__ Cout,
                                                 int M, int N, int K) {
    __shared__ u16 As[64][40];   // padded: 80B row stride -> ~2-way LDS aliasing
    __shared__ u16 Bs[96][40];
    int t = threadIdx.x;
    int m0 = blockIdx.y * 64;
    int n0 = blockIdx.x * 96;
    int w = t >> 6, lane = t & 63;
    int wm = w >> 1, wn = w & 1;
    int lrow = lane & 15;
    int lk8 = (lane >> 4) * 8;

    f32x4 acc[2][3];
#pragma unroll
    for (int i = 0; i < 2; ++i)
#pragma unroll
        for (int f = 0; f < 3; ++f)
#pragma unroll
            for (int r = 0; r < 4; ++r) acc[i][f][r] = 0.f;

    int arow = t >> 2, aseg = (t & 3) * 8;
    const u16* Aptr = A + (size_t)(m0 + arow) * K + aseg;

    for (int k0 = 0; k0 < K; k0 += 32) {
        *reinterpret_cast<u16x8*>(&As[arow][aseg]) =
            *reinterpret_cast<const u16x8*>(Aptr + k0);
#pragma unroll
        for (int i2 = 0; i2 < 2; ++i2) {
            int idx = t + i2 * 256;
            if (idx < 384) {
                int br = idx >> 2, bseg = (idx & 3) * 8;
                *reinterpret_cast<u16x8*>(&Bs[br][bseg]) =
                    *reinterpret_cast<const u16x8*>(Bt + (size_t)(n0 + br) * K + k0 + bseg);
            }
        }
        __syncthreads();
        bf16x8 af[2], bfr[3];
#pragma unroll
        for (int i = 0; i < 2; ++i)
            af[i] = *reinterpret_cast<const bf16x8*>(&As[wm * 32 + i * 16 + lrow][lk8]);
#pragma unroll
        for (int f = 0; f < 3; ++f)
            bfr[f] = *reinterpret_cast<const bf16x8*>(&Bs[wn * 48 + f * 16 + lrow][lk8]);
#pragma unroll
        for (int i = 0; i < 2; ++i)
#pragma unroll
            for (int f = 0; f < 3; ++f)
                acc[i][f] = __builtin_amdgcn_mfma_f32_16x16x32_bf16(af[i], bfr[f], acc[i][f], 0, 0, 0);
        __syncthreads();
    }

#pragma unroll
    for (int i = 0; i < 2; ++i) {
#pragma unroll
        for (int f = 0; f < 3; ++f) {
            int n = n0 + wn * 48 + f * 16 + lrow;
            float bvn = bias[n];
#pragma unroll
            for (int r = 0; r < 4; ++r) {
                int m = m0 + wm * 32 + i * 16 + (lane >> 4) * 4 + r;
                float v = acc[i][f][r] + bvn;
                if (EPI == 1 || EPI == 3) v += add[(size_t)m * N + n];
                if (EPI == 2) {
                    float g = 0.5f * v * (1.0f + erff(v * 0.70710678118654752f));
                    ((u16*)Cout)[(size_t)m * N + n] = f2b(g);
                } else {
                    ((float*)Cout)[(size_t)m * N + n] = v;
                }
            }
        }
    }
}

// ---------------------------------------------------------------------------
// Deformable sampling. proj rows: [value(192) | off(72) | aw_logits(24)] fp32
// One 32-lane group per (b, l, head); lane = channel within head. bf16 out.
// ---------------------------------------------------------------------------
__global__ __launch_bounds__(256) void deform_kernel(const float* __restrict__ proj,
                                                     u16* __restrict__ dout) {
    int g = blockIdx.x * 8 + (threadIdx.x >> 5);
    int lane = threadIdx.x & 31;
    int h = g % NH;
    int tmp = g / NH;
    int l = tmp % LL;
    int b = tmp / LL;

    int d = l >> 10;
    int rem = l & 1023;
    int y = rem >> 5;
    int xw = rem & 31;

    const float* rowp = proj + (size_t)(b * LL + l) * NPROJ;

    float lg0 = rowp[264 + h * 4 + 0];
    float lg1 = rowp[264 + h * 4 + 1];
    float lg2 = rowp[264 + h * 4 + 2];
    float lg3 = rowp[264 + h * 4 + 3];
    float mx = fmaxf(fmaxf(lg0, lg1), fmaxf(lg2, lg3));
    float e0 = __expf(lg0 - mx), e1 = __expf(lg1 - mx);
    float e2 = __expf(lg2 - mx), e3 = __expf(lg3 - mx);
    float inv = 1.0f / (e0 + e1 + e2 + e3);
    float awv[4] = {e0 * inv, e1 * inv, e2 * inv, e3 * inv};

    const float* vbase = proj + (size_t)b * LL * NPROJ + h * HD + lane;
    float acc = 0.f;
#pragma unroll
    for (int p = 0; p < PP; ++p) {
        float od = rowp[192 + (h * PP + p) * 3 + 0];
        float ox = rowp[192 + (h * PP + p) * 3 + 1];
        float oy = rowp[192 + (h * PP + p) * 3 + 2];
        float pd = (d + 0.5f) + od - 0.5f;
        float px = (xw + 0.5f) + ox - 0.5f;
        float py = (y + 0.5f) + oy - 0.5f;
        float d0f = floorf(pd), x0f = floorf(px), y0f = floorf(py);
        float fd = pd - d0f, fx = px - x0f, fy = py - y0f;
        int d0 = (int)d0f, x0 = (int)x0f, y0 = (int)y0f;
        float awp = awv[p];
#pragma unroll
        for (int dd = 0; dd < 2; ++dd) {
#pragma unroll
            for (int dy = 0; dy < 2; ++dy) {
#pragma unroll
                for (int dx = 0; dx < 2; ++dx) {
                    int di = d0 + dd, yi = y0 + dy, xi = x0 + dx;
                    bool inb = (di >= 0) & (di < SS) & (yi >= 0) & (yi < HH) &
                               (xi >= 0) & (xi < WW);
                    if (inb) {
                        float wgt = (dd ? fd : 1.f - fd) * (dy ? fy : 1.f - fy) *
                                    (dx ? fx : 1.f - fx);
                        int idx = (di * HH + yi) * WW + xi;
                        acc += awp * wgt * vbase[(size_t)idx * NPROJ];
                    }
                }
            }
        }
    }
    dout[(size_t)(b * LL + l) * CC + h * HD + lane] = f2b(acc);
}

// ---------------------------------------------------------------------------
// LayerNorm over C=192, one wave per row; bf16 output (fc1 input).
// ---------------------------------------------------------------------------
__global__ __launch_bounds__(256) void layernorm_kernel(const float* __restrict__ hin,
                                                        const float* __restrict__ g2,
                                                        const float* __restrict__ b2,
                                                        u16* __restrict__ lnout) {
    int row = blockIdx.x * 4 + (threadIdx.x >> 6);
    int lane = threadIdx.x & 63;
    const float* hr = hin + (size_t)row * CC;
    float v0 = hr[lane], v1 = hr[lane + 64], v2 = hr[lane + 128];
    float s = v0 + v1 + v2;
    float sq = v0 * v0 + v1 * v1 + v2 * v2;
#pragma unroll
    for (int o = 32; o > 0; o >>= 1) {
        s += __shfl_xor(s, o);
        sq += __shfl_xor(sq, o);
    }
    float m = s * (1.0f / CC);
    float var = sq * (1.0f / CC) - m * m;
    float r = rsqrtf(var + 1e-5f);
    u16* lo = lnout + (size_t)row * CC;
    lo[lane]       = f2b((v0 - m) * r * g2[lane]       + b2[lane]);
    lo[lane + 64]  = f2b((v1 - m) * r * g2[lane + 64]  + b2[lane + 64]);
    lo[lane + 128] = f2b((v2 - m) * r * g2[lane + 128] + b2[lane + 128]);
}

// ---------------------------------------------------------------------------
extern "C" void kernel_launch(void* const* d_in, const int* in_sizes, int n_in,
                              void* d_out, int out_size, void* d_ws, size_t ws_size,
                              hipStream_t stream) {
    const float* x    = (const float*)d_in[0];
    const float* Wv   = (const float*)d_in[2];
    const float* bv   = (const float*)d_in[3];
    const float* Woff = (const float*)d_in[4];
    const float* boff = (const float*)d_in[5];
    const float* Waw  = (const float*)d_in[6];
    const float* baw  = (const float*)d_in[7];
    const float* Wout = (const float*)d_in[8];
    const float* bout = (const float*)d_in[9];
    const float* g2   = (const float*)d_in[10];
    const float* b2   = (const float*)d_in[11];
    const float* W1   = (const float*)d_in[12];
    const float* b1   = (const float*)d_in[13];
    const float* W2   = (const float*)d_in[14];
    const float* b2m  = (const float*)d_in[15];

    char* wsb = (char*)d_ws;
    // Region A [0, 50.3MB): proj fp32 (37.7MB) early, then hid bf16 (50.3MB)
    float* proj = (float*)(wsb + 0);
    u16*   hid  = (u16*)(wsb + 0);
    float* hbuf = (float*)(wsb + 50331648);      // 25.2MB fp32
    u16*   dbuf = (u16*)(wsb + 75497472);        // 12.6MB bf16
    float* h2   = (float*)(wsb + 75497472);      // 25.2MB fp32 (overlaps dbuf+ln, both dead)
    u16*   xp   = (u16*)(wsb + 88080384);        // 12.6MB bf16
    u16*   ln   = (u16*)(wsb + 88080384);        // same region (xp dead after proj gemm)
    u16*   wcatT = (u16*)(wsb + 100663296);
    u16*   woutT = wcatT + NPROJ * CC;
    u16*   w1T   = woutT + CC * CC;
    u16*   w2T   = w1T + HID * CC;
    float* bcat  = (float*)(w2T + CC * HID);
    float* out   = (float*)d_out;

    int wtot = NPROJ * CC + CC * CC + HID * CC + CC * HID + NPROJ;
    build_weights<<<(wtot + 255) / 256, 256, 0, stream>>>(
        Wv, Woff, Waw, Wout, W1, W2, bv, boff, baw, wcatT, woutT, w1T, w2T, bcat);
    transpose_in<<<dim3(LL / 32, CC / 32, BB), dim3(32, 8), 0, stream>>>(x, xp);
    gemm_mfma<0><<<dim3(NPROJ / 96, MTOK / 64), 256, 0, stream>>>(
        xp, wcatT, bcat, nullptr, proj, MTOK, NPROJ, CC);
    deform_kernel<<<(BB * LL * NH) / 8, 256, 0, stream>>>(proj, dbuf);
    gemm_mfma<1><<<dim3(CC / 96, MTOK / 64), 256, 0, stream>>>(
        dbuf, woutT, bout, x /* shortcut */, hbuf, MTOK, CC, CC);
    layernorm_kernel<<<MTOK / 4, 256, 0, stream>>>(hbuf, g2, b2, ln);
    gemm_mfma<2><<<dim3(HID / 96, MTOK / 64), 256, 0, stream>>>(
        ln, w1T, b1, nullptr, hid, MTOK, HID, CC);
    gemm_mfma<3><<<dim3(CC / 96, MTOK / 64), 256, 0, stream>>>(
        hid, w2T, b2m, hbuf, h2, MTOK, CC, HID);
    transpose_out<<<dim3(LL / 32, CC / 32, BB), dim3(32, 8), 0, stream>>>(h2, out);
}

// Round 4
// 285.661 us; speedup vs baseline: 3.0081x; 1.2324x over previous
//
#include <hip/hip_runtime.h>
#include <hip/hip_bf16.h>
#include <math.h>

// Problem constants
#define BB 2
#define CC 192
#define SS 16
#define HH 32
#define WW 32
#define NH 6
#define PP 4
#define HD 32
#define HID 768
#define LL (SS * HH * WW)        // 16384
#define MTOK (BB * LL)           // 32768 tokens
#define NPROJ 288                // 192 (value) + 72 (off) + 24 (aw)

typedef unsigned short u16;
typedef u16 u16x8 __attribute__((ext_vector_type(8)));
typedef __bf16 bf16x8 __attribute__((ext_vector_type(8)));
typedef float f32x4 __attribute__((ext_vector_type(4)));

static __device__ __forceinline__ u16 f2b(float f) {
    __hip_bfloat16 h = __float2bfloat16(f);
    return *reinterpret_cast<u16*>(&h);
}

// ---------------------------------------------------------------------------
// Build all bf16 transposed weights (N x K layout) + concatenated bias (fp32)
// ---------------------------------------------------------------------------
__global__ void build_weights(const float* __restrict__ Wv, const float* __restrict__ Woff,
                              const float* __restrict__ Waw, const float* __restrict__ Wout,
                              const float* __restrict__ W1, const float* __restrict__ W2,
                              const float* __restrict__ bv, const float* __restrict__ boff,
                              const float* __restrict__ baw,
                              u16* __restrict__ wcatT, u16* __restrict__ woutT,
                              u16* __restrict__ w1T, u16* __restrict__ w2T,
                              float* __restrict__ bcat) {
    int i = blockIdx.x * 256 + threadIdx.x;
    if (i < NPROJ * CC) {                       // wcatT[n][k] = Wcat[k][n]
        int n = i / CC, k = i % CC;
        float v = (n < 192) ? Wv[k * 192 + n]
                : (n < 264) ? Woff[k * 72 + (n - 192)]
                            : Waw[k * 24 + (n - 264)];
        wcatT[i] = f2b(v);
        return;
    }
    i -= NPROJ * CC;
    if (i < CC * CC) {
        int n = i / CC, k = i % CC;
        woutT[i] = f2b(Wout[k * CC + n]);
        return;
    }
    i -= CC * CC;
    if (i < HID * CC) {
        int n = i / CC, k = i % CC;
        w1T[i] = f2b(W1[k * HID + n]);
        return;
    }
    i -= HID * CC;
    if (i < CC * HID) {
        int n = i / HID, k = i % HID;
        w2T[i] = f2b(W2[k * CC + n]);
        return;
    }
    i -= CC * HID;
    if (i < NPROJ) {
        float v = (i < 192) ? bv[i] : (i < 264) ? boff[i - 192] : baw[i - 264];
        bcat[i] = v;
    }
}

// ---------------------------------------------------------------------------
// x (B, C, L) channel-major  ->  xp (B, L, C) token-major bf16
// ---------------------------------------------------------------------------
__global__ void transpose_in(const float* __restrict__ x, u16* __restrict__ xp) {
    __shared__ float s[32][33];
    int b = blockIdx.z;
    int c0 = blockIdx.y * 32;
    int l0 = blockIdx.x * 32;
    int tx = threadIdx.x, ty = threadIdx.y;
#pragma unroll
    for (int r = 0; r < 32; r += 8)
        s[ty + r][tx] = x[((size_t)b * CC + c0 + ty + r) * LL + l0 + tx];
    __syncthreads();
#pragma unroll
    for (int r = 0; r < 32; r += 8)
        xp[((size_t)b * LL + l0 + ty + r) * CC + c0 + tx] = f2b(s[tx][ty + r]);
}

// ---------------------------------------------------------------------------
// MFMA bf16 GEMM: C(MxN) = A(MxK) @ Bt(NxK)^T + bias
// BM=128, BN=96, BK=32. 256 threads = 4 waves (2x2), each wave 64x48.
// EPI: 0 = split write: n<192 -> vbuf bf16 (B,NH,L,HD); n>=192 -> offaw fp32 (M,96)
//      1 = fp32 out + bias + add       (wout + shortcut), token-major
//      2 = bf16 out gelu(acc + bias)   (fc1), token-major
//      3 = fp32 out + bias + add, written CHANNEL-MAJOR (B,C,L)  (fc2 + residual)
// ---------------------------------------------------------------------------
template<int EPI>
__global__ __launch_bounds__(256) void gemm_mfma(const u16* __restrict__ A,
                                                 const u16* __restrict__ Bt,
                                                 const float* __restrict__ bias,
                                                 const float* __restrict__ add,
                                                 void* __restrict__ Cout,
                                                 void* __restrict__ Cout2,
                                                 int M, int N, int K) {
    __shared__ u16 As[128][40];   // pad 40: 80B stride -> 2-way aliasing (free)
    __shared__ u16 Bs[96][40];
    int t = threadIdx.x;
    int m0 = blockIdx.y * 128;
    int n0 = blockIdx.x * 96;
    int w = t >> 6, lane = t & 63;
    int wm = w >> 1, wn = w & 1;            // wave tile 64 x 48
    int lrow = lane & 15;
    int lk8 = (lane >> 4) * 8;

    f32x4 acc[4][3];
#pragma unroll
    for (int i = 0; i < 4; ++i)
#pragma unroll
        for (int f = 0; f < 3; ++f)
#pragma unroll
            for (int r = 0; r < 4; ++r) acc[i][f][r] = 0.f;

    int arow = t >> 2, aseg = (t & 3) * 8;
    int br0 = t >> 2, bseg0 = (t & 3) * 8;
    int idx1 = t + 256;
    int br1 = idx1 >> 2, bseg1 = (idx1 & 3) * 8;

    for (int k0 = 0; k0 < K; k0 += 32) {
        *reinterpret_cast<u16x8*>(&As[arow][aseg]) =
            *reinterpret_cast<const u16x8*>(A + (size_t)(m0 + arow) * K + k0 + aseg);
        *reinterpret_cast<u16x8*>(&As[arow + 64][aseg]) =
            *reinterpret_cast<const u16x8*>(A + (size_t)(m0 + arow + 64) * K + k0 + aseg);
        *reinterpret_cast<u16x8*>(&Bs[br0][bseg0]) =
            *reinterpret_cast<const u16x8*>(Bt + (size_t)(n0 + br0) * K + k0 + bseg0);
        if (idx1 < 384)
            *reinterpret_cast<u16x8*>(&Bs[br1][bseg1]) =
                *reinterpret_cast<const u16x8*>(Bt + (size_t)(n0 + br1) * K + k0 + bseg1);
        __syncthreads();
        bf16x8 af[4], bfr[3];
#pragma unroll
        for (int i = 0; i < 4; ++i)
            af[i] = *reinterpret_cast<const bf16x8*>(&As[wm * 64 + i * 16 + lrow][lk8]);
#pragma unroll
        for (int f = 0; f < 3; ++f)
            bfr[f] = *reinterpret_cast<const bf16x8*>(&Bs[wn * 48 + f * 16 + lrow][lk8]);
#pragma unroll
        for (int i = 0; i < 4; ++i)
#pragma unroll
            for (int f = 0; f < 3; ++f)
                acc[i][f] = __builtin_amdgcn_mfma_f32_16x16x32_bf16(af[i], bfr[f], acc[i][f], 0, 0, 0);
        __syncthreads();
    }

#pragma unroll
    for (int i = 0; i < 4; ++i) {
#pragma unroll
        for (int f = 0; f < 3; ++f) {
            int n = n0 + wn * 48 + f * 16 + lrow;
            float bvn = bias[n];
            int mb = m0 + wm * 64 + i * 16 + (lane >> 4) * 4;
            if (EPI == 3) {
                // channel-major float4 write: out[(b*C + n)*L + l..l+3]
                float4 vv;
#pragma unroll
                for (int r = 0; r < 4; ++r)
                    ((float*)&vv)[r] = acc[i][f][r] + bvn + add[(size_t)(mb + r) * N + n];
                int b = mb >> 14, l = mb & (LL - 1);
                *reinterpret_cast<float4*>((float*)Cout + ((size_t)b * CC + n) * LL + l) = vv;
            } else {
#pragma unroll
                for (int r = 0; r < 4; ++r) {
                    int m = mb + r;
                    float v = acc[i][f][r] + bvn;
                    if (EPI == 0) {
                        if (n < 192) {
                            int h = n >> 5, hd = n & 31;
                            int b = m >> 14, l = m & (LL - 1);
                            ((u16*)Cout)[(((size_t)b * NH + h) * LL + l) * HD + hd] = f2b(v);
                        } else {
                            ((float*)Cout2)[(size_t)m * 96 + (n - 192)] = v;
                        }
                    } else if (EPI == 1) {
                        v += add[(size_t)m * N + n];
                        ((float*)Cout)[(size_t)m * N + n] = v;
                    } else { // EPI == 2
                        float g = 0.5f * v * (1.0f + erff(v * 0.70710678118654752f));
                        ((u16*)Cout)[(size_t)m * N + n] = f2b(g);
                    }
                }
            }
        }
    }
}

// ---------------------------------------------------------------------------
// Deformable sampling, cooperative-corner version.
// 32-lane group per (b,l,head). Lane j plays two roles:
//   role 1: computes corner j's (byte offset, weight*aw)  [p = j>>3, corner = j&7]
//   role 2: accumulates channel j over all 32 corners via __shfl broadcast.
// vbuf: bf16 (B,NH,L,HD); offaw: fp32 (B*L, 96) = [off(72) | aw_logits(24)]
// ---------------------------------------------------------------------------
__global__ __launch_bounds__(256) void deform_kernel(const u16* __restrict__ vbuf,
                                                     const float* __restrict__ offaw,
                                                     u16* __restrict__ dout) {
    int g = blockIdx.x * 8 + (threadIdx.x >> 5);
    int j = threadIdx.x & 31;
    int h = g % NH;
    int tmp = g / NH;
    int l = tmp % LL;
    int b = tmp / LL;
    int d = l >> 10, rem = l & 1023, y = rem >> 5, xw = rem & 31;

    const float* oa = offaw + (size_t)(b * LL + l) * 96;
    int p = j >> 3, cor = j & 7;
    int dx = cor & 1, dy = (cor >> 1) & 1, dd = cor >> 2;

    // softmax over the 4 attention logits (replicated, cheap)
    float4 lg = *reinterpret_cast<const float4*>(oa + 72 + h * 4);
    float mx = fmaxf(fmaxf(lg.x, lg.y), fmaxf(lg.z, lg.w));
    float e0 = __expf(lg.x - mx), e1 = __expf(lg.y - mx);
    float e2 = __expf(lg.z - mx), e3 = __expf(lg.w - mx);
    float inv = 1.0f / (e0 + e1 + e2 + e3);
    float ep = (p == 0) ? e0 : (p == 1) ? e1 : (p == 2) ? e2 : e3;
    float awp = ep * inv;

    const float* op = oa + (h * 4 + p) * 3;
    float pd = (d + 0.5f) + op[0] - 0.5f;
    float px = (xw + 0.5f) + op[1] - 0.5f;
    float py = (y + 0.5f) + op[2] - 0.5f;
    float d0f = floorf(pd), x0f = floorf(px), y0f = floorf(py);
    float fd = pd - d0f, fx = px - x0f, fy = py - y0f;
    int di = (int)d0f + dd, yi = (int)y0f + dy, xi = (int)x0f + dx;
    bool inb = (di >= 0) & (di < SS) & (yi >= 0) & (yi < HH) & (xi >= 0) & (xi < WW);
    float wgt = (dd ? fd : 1.f - fd) * (dy ? fy : 1.f - fy) * (dx ? fx : 1.f - fx) * awp;
    wgt = inb ? wgt : 0.f;
    int dic = min(max(di, 0), SS - 1);
    int yic = min(max(yi, 0), HH - 1);
    int xic = min(max(xi, 0), WW - 1);
    int bo = (((dic * HH) + yic) * WW + xic) * (HD * 2);   // byte offset into head plane

    const char* vhead = (const char*)(vbuf + ((size_t)(b * NH + h) * LL) * HD) + 2 * j;
    float acc = 0.f;
#pragma unroll 8
    for (int jj = 0; jj < 32; ++jj) {
        int boj = __shfl(bo, jj, 32);
        float wj = __shfl(wgt, jj, 32);
        u16 v = *reinterpret_cast<const u16*>(vhead + boj);
        acc += wj * __uint_as_float(((unsigned)v) << 16);
    }
    dout[(size_t)(b * LL + l) * CC + h * HD + j] = f2b(acc);
}

// ---------------------------------------------------------------------------
// LayerNorm over C=192, one wave per row; bf16 output (fc1 input).
// ---------------------------------------------------------------------------
__global__ __launch_bounds__(256) void layernorm_kernel(const float* __restrict__ hin,
                                                        const float* __restrict__ g2,
                                                        const float* __restrict__ b2,
                                                        u16* __restrict__ lnout) {
    int row = blockIdx.x * 4 + (threadIdx.x >> 6);
    int lane = threadIdx.x & 63;
    const float* hr = hin + (size_t)row * CC;
    float v0 = hr[lane], v1 = hr[lane + 64], v2 = hr[lane + 128];
    float s = v0 + v1 + v2;
    float sq = v0 * v0 + v1 * v1 + v2 * v2;
#pragma unroll
    for (int o = 32; o > 0; o >>= 1) {
        s += __shfl_xor(s, o);
        sq += __shfl_xor(sq, o);
    }
    float m = s * (1.0f / CC);
    float var = sq * (1.0f / CC) - m * m;
    float r = rsqrtf(var + 1e-5f);
    u16* lo = lnout + (size_t)row * CC;
    lo[lane]       = f2b((v0 - m) * r * g2[lane]       + b2[lane]);
    lo[lane + 64]  = f2b((v1 - m) * r * g2[lane + 64]  + b2[lane + 64]);
    lo[lane + 128] = f2b((v2 - m) * r * g2[lane + 128] + b2[lane + 128]);
}

// ---------------------------------------------------------------------------
extern "C" void kernel_launch(void* const* d_in, const int* in_sizes, int n_in,
                              void* d_out, int out_size, void* d_ws, size_t ws_size,
                              hipStream_t stream) {
    const float* x    = (const float*)d_in[0];
    const float* Wv   = (const float*)d_in[2];
    const float* bv   = (const float*)d_in[3];
    const float* Woff = (const float*)d_in[4];
    const float* boff = (const float*)d_in[5];
    const float* Waw  = (const float*)d_in[6];
    const float* baw  = (const float*)d_in[7];
    const float* Wout = (const float*)d_in[8];
    const float* bout = (const float*)d_in[9];
    const float* g2   = (const float*)d_in[10];
    const float* b2   = (const float*)d_in[11];
    const float* W1   = (const float*)d_in[12];
    const float* b1   = (const float*)d_in[13];
    const float* W2   = (const float*)d_in[14];
    const float* b2m  = (const float*)d_in[15];

    char* wsb = (char*)d_ws;
    // Lifetimes: xp[p3] vbuf[p4] offaw[p4] dbuf[p5] hbuf[p8] ln[p7] hid[p8]
    u16*   xp    = (u16*)(wsb + 0);              // [0, 12.6M)
    u16*   vbuf  = (u16*)(wsb + 12582912);       // [12.6M, 25.2M)
    float* offaw = (float*)(wsb + 25165824);     // [25.2M, 37.8M)
    u16*   dbuf  = (u16*)(wsb + 0);              // reuses xp (dead after proj gemm)
    u16*   hid   = (u16*)(wsb + 12582912);       // reuses vbuf+offaw (dead after deform)
    float* hbuf  = (float*)(wsb + 66060288);     // [63M, 88.2M)
    u16*   ln    = (u16*)(wsb + 92274688);       // [88.2M, 100.8M)
    u16*   wcatT = (u16*)(wsb + 105906176);      // [101M, ...)
    u16*   woutT = wcatT + NPROJ * CC;
    u16*   w1T   = woutT + CC * CC;
    u16*   w2T   = w1T + HID * CC;
    float* bcat  = (float*)(w2T + CC * HID);
    float* out   = (float*)d_out;

    int wtot = NPROJ * CC + CC * CC + HID * CC + CC * HID + NPROJ;
    build_weights<<<(wtot + 255) / 256, 256, 0, stream>>>(
        Wv, Woff, Waw, Wout, W1, W2, bv, boff, baw, wcatT, woutT, w1T, w2T, bcat);
    transpose_in<<<dim3(LL / 32, CC / 32, BB), dim3(32, 8), 0, stream>>>(x, xp);
    gemm_mfma<0><<<dim3(NPROJ / 96, MTOK / 128), 256, 0, stream>>>(
        xp, wcatT, bcat, nullptr, vbuf, offaw, MTOK, NPROJ, CC);
    deform_kernel<<<(BB * LL * NH) / 8, 256, 0, stream>>>(vbuf, offaw, dbuf);
    gemm_mfma<1><<<dim3(CC / 96, MTOK / 128), 256, 0, stream>>>(
        dbuf, woutT, bout, x /* shortcut */, hbuf, nullptr, MTOK, CC, CC);
    layernorm_kernel<<<MTOK / 4, 256, 0, stream>>>(hbuf, g2, b2, ln);
    gemm_mfma<2><<<dim3(HID / 96, MTOK / 128), 256, 0, stream>>>(
        ln, w1T, b1, nullptr, hid, nullptr, MTOK, HID, CC);
    gemm_mfma<3><<<dim3(CC / 96, MTOK / 128), 256, 0, stream>>>(
        hid, w2T, b2m, hbuf, out, nullptr, MTOK, CC, HID);
}

// Round 6
// 284.710 us; speedup vs baseline: 3.0182x; 1.0033x over previous
//
#include <hip/hip_runtime.h>
#include <hip/hip_bf16.h>
#include <math.h>

// Problem constants
#define BB 2
#define CC 192
#define SS 16
#define HH 32
#define WW 32
#define NH 6
#define PP 4
#define HD 32
#define HID 768
#define LL (SS * HH * WW)        // 16384
#define MTOK (BB * LL)           // 32768 tokens
#define NPROJ 288                // 192 (value) + 72 (off) + 24 (aw)

typedef unsigned short u16;
typedef u16 u16x8 __attribute__((ext_vector_type(8)));
typedef __bf16 bf16x8 __attribute__((ext_vector_type(8)));
typedef float f32x4 __attribute__((ext_vector_type(4)));

static __device__ __forceinline__ u16 f2b(float f) {
    __hip_bfloat16 h = __float2bfloat16(f);
    return *reinterpret_cast<u16*>(&h);
}

// ---------------------------------------------------------------------------
// Build all bf16 transposed weights (N x K layout) + concatenated bias (fp32)
// ---------------------------------------------------------------------------
__global__ void build_weights(const float* __restrict__ Wv, const float* __restrict__ Woff,
                              const float* __restrict__ Waw, const float* __restrict__ Wout,
                              const float* __restrict__ W1, const float* __restrict__ W2,
                              const float* __restrict__ bv, const float* __restrict__ boff,
                              const float* __restrict__ baw,
                              u16* __restrict__ wcatT, u16* __restrict__ woutT,
                              u16* __restrict__ w1T, u16* __restrict__ w2T,
                              float* __restrict__ bcat) {
    int i = blockIdx.x * 256 + threadIdx.x;
    if (i < NPROJ * CC) {                       // wcatT[n][k] = Wcat[k][n]
        int n = i / CC, k = i % CC;
        float v = (n < 192) ? Wv[k * 192 + n]
                : (n < 264) ? Woff[k * 72 + (n - 192)]
                            : Waw[k * 24 + (n - 264)];
        wcatT[i] = f2b(v);
        return;
    }
    i -= NPROJ * CC;
    if (i < CC * CC) {
        int n = i / CC, k = i % CC;
        woutT[i] = f2b(Wout[k * CC + n]);
        return;
    }
    i -= CC * CC;
    if (i < HID * CC) {
        int n = i / CC, k = i % CC;
        w1T[i] = f2b(W1[k * HID + n]);
        return;
    }
    i -= HID * CC;
    if (i < CC * HID) {
        int n = i / HID, k = i % HID;
        w2T[i] = f2b(W2[k * CC + n]);
        return;
    }
    i -= CC * HID;
    if (i < NPROJ) {
        float v = (i < 192) ? bv[i] : (i < 264) ? boff[i - 192] : baw[i - 264];
        bcat[i] = v;
    }
}

// ---------------------------------------------------------------------------
// x (B, C, L) channel-major  ->  xp (B, L, C) token-major bf16
// ---------------------------------------------------------------------------
__global__ void transpose_in(const float* __restrict__ x, u16* __restrict__ xp) {
    __shared__ float s[32][33];
    int b = blockIdx.z;
    int c0 = blockIdx.y * 32;
    int l0 = blockIdx.x * 32;
    int tx = threadIdx.x, ty = threadIdx.y;
#pragma unroll
    for (int r = 0; r < 32; r += 8)
        s[ty + r][tx] = x[((size_t)b * CC + c0 + ty + r) * LL + l0 + tx];
    __syncthreads();
#pragma unroll
    for (int r = 0; r < 32; r += 8)
        xp[((size_t)b * LL + l0 + ty + r) * CC + c0 + tx] = f2b(s[tx][ty + r]);
}

// ---------------------------------------------------------------------------
// MFMA bf16 GEMM: C(MxN) = A(MxK) @ Bt(NxK)^T + bias
// BM=128, BN=192, BK=32. 256 threads = 4 waves (2x2), each wave 64x96 (4x6).
// EPI: 0 = split write: n<192 -> vbuf bf16 (B,NH,L,HD); 192<=n<288 -> offaw fp32
//      1 = fp32 out + bias + add       (wout + shortcut), token-major
//      2 = bf16 out gelu(acc + bias)   (fc1), token-major
//      3 = fp32 out + bias + add, written CHANNEL-MAJOR (B,C,L)  (fc2 + residual)
// ---------------------------------------------------------------------------
template<int EPI>
__global__ __launch_bounds__(256, 2) void gemm_mfma(const u16* __restrict__ A,
                                                    const u16* __restrict__ Bt,
                                                    const float* __restrict__ bias,
                                                    const float* __restrict__ add,
                                                    void* __restrict__ Cout,
                                                    void* __restrict__ Cout2,
                                                    int M, int N, int K) {
    __shared__ u16 As[128][40];   // pad 40: 80B stride, 16B-aligned rows
    __shared__ u16 Bs[192][40];
    int t = threadIdx.x;
    int m0 = blockIdx.y * 128;
    int n0 = blockIdx.x * 192;
    int w = t >> 6, lane = t & 63;
    int wm = w >> 1, wn = w & 1;            // wave tile 64 x 96
    int lrow = lane & 15;
    int lk8 = (lane >> 4) * 8;

    f32x4 acc[4][6];
#pragma unroll
    for (int i = 0; i < 4; ++i)
#pragma unroll
        for (int f = 0; f < 6; ++f)
#pragma unroll
            for (int r = 0; r < 4; ++r) acc[i][f][r] = 0.f;

    int arow = t >> 2, aseg = (t & 3) * 8;

    for (int k0 = 0; k0 < K; k0 += 32) {
        *reinterpret_cast<u16x8*>(&As[arow][aseg]) =
            *reinterpret_cast<const u16x8*>(A + (size_t)(m0 + arow) * K + k0 + aseg);
        *reinterpret_cast<u16x8*>(&As[arow + 64][aseg]) =
            *reinterpret_cast<const u16x8*>(A + (size_t)(m0 + arow + 64) * K + k0 + aseg);
#pragma unroll
        for (int i2 = 0; i2 < 3; ++i2) {
            int idx = t + i2 * 256;
            int br = idx >> 2, bseg = (idx & 3) * 8;
            int brn = n0 + br; if (brn > N - 1) brn = N - 1;   // clamp (proj tail)
            *reinterpret_cast<u16x8*>(&Bs[br][bseg]) =
                *reinterpret_cast<const u16x8*>(Bt + (size_t)brn * K + k0 + bseg);
        }
        __syncthreads();
        bf16x8 af[4], bfr[6];
#pragma unroll
        for (int i = 0; i < 4; ++i)
            af[i] = *reinterpret_cast<const bf16x8*>(&As[wm * 64 + i * 16 + lrow][lk8]);
#pragma unroll
        for (int f = 0; f < 6; ++f)
            bfr[f] = *reinterpret_cast<const bf16x8*>(&Bs[wn * 96 + f * 16 + lrow][lk8]);
#pragma unroll
        for (int i = 0; i < 4; ++i)
#pragma unroll
            for (int f = 0; f < 6; ++f)
                acc[i][f] = __builtin_amdgcn_mfma_f32_16x16x32_bf16(af[i], bfr[f], acc[i][f], 0, 0, 0);
        __syncthreads();
    }

#pragma unroll
    for (int i = 0; i < 4; ++i) {
#pragma unroll
        for (int f = 0; f < 6; ++f) {
            int n = n0 + wn * 96 + f * 16 + lrow;
            if (n >= N) continue;
            float bvn = bias[n];
            int mb = m0 + wm * 64 + i * 16 + (lane >> 4) * 4;
            if (EPI == 3) {
                float4 vv;
#pragma unroll
                for (int r = 0; r < 4; ++r)
                    ((float*)&vv)[r] = acc[i][f][r] + bvn + add[(size_t)(mb + r) * N + n];
                int b = mb >> 14, l = mb & (LL - 1);
                *reinterpret_cast<float4*>((float*)Cout + ((size_t)b * CC + n) * LL + l) = vv;
            } else {
#pragma unroll
                for (int r = 0; r < 4; ++r) {
                    int m = mb + r;
                    float v = acc[i][f][r] + bvn;
                    if (EPI == 0) {
                        if (n < 192) {
                            int h = n >> 5, hd = n & 31;
                            int b = m >> 14, l = m & (LL - 1);
                            ((u16*)Cout)[(((size_t)b * NH + h) * LL + l) * HD + hd] = f2b(v);
                        } else {
                            ((float*)Cout2)[(size_t)m * 96 + (n - 192)] = v;
                        }
                    } else if (EPI == 1) {
                        v += add[(size_t)m * N + n];
                        ((float*)Cout)[(size_t)m * N + n] = v;
                    } else { // EPI == 2
                        float g = 0.5f * v * (1.0f + erff(v * 0.70710678118654752f));
                        ((u16*)Cout)[(size_t)m * N + n] = f2b(g);
                    }
                }
            }
        }
    }
}

// ---------------------------------------------------------------------------
// Deformable sampling, LDS-broadcast version.
// 32-lane group per (b,l,head). Lane j computes corner j's (byte offset,
// weight*aw), stores the pair to LDS; after one barrier every lane (=channel j)
// reads all 32 pairs back via uniform-address ds_read_b128 (broadcast) and
// accumulates 32 scattered bf16 gathers, fully unrolled.
// vbuf: bf16 (B,NH,L,HD); offaw: fp32 (B*L, 96) = [off(72) | aw_logits(24)]
// ---------------------------------------------------------------------------
__global__ __launch_bounds__(256) void deform_kernel(const u16* __restrict__ vbuf,
                                                     const float* __restrict__ offaw,
                                                     u16* __restrict__ dout) {
    __shared__ uint2 cw[8][32];
    int gl = threadIdx.x >> 5;
    int g = blockIdx.x * 8 + gl;
    int j = threadIdx.x & 31;
    int h = g % NH;
    int tmp = g / NH;
    int l = tmp % LL;
    int b = tmp / LL;
    int d = l >> 10, rem = l & 1023, y = rem >> 5, xw = rem & 31;

    const float* oa = offaw + (size_t)(b * LL + l) * 96;
    int p = j >> 3, cor = j & 7;
    int dx = cor & 1, dy = (cor >> 1) & 1, dd = cor >> 2;

    float4 lg = *reinterpret_cast<const float4*>(oa + 72 + h * 4);
    float mx = fmaxf(fmaxf(lg.x, lg.y), fmaxf(lg.z, lg.w));
    float e0 = __expf(lg.x - mx), e1 = __expf(lg.y - mx);
    float e2 = __expf(lg.z - mx), e3 = __expf(lg.w - mx);
    float inv = 1.0f / (e0 + e1 + e2 + e3);
    float ep = (p == 0) ? e0 : (p == 1) ? e1 : (p == 2) ? e2 : e3;
    float awp = ep * inv;

    const float* op = oa + (h * 4 + p) * 3;
    float pd = (d + 0.5f) + op[0] - 0.5f;
    float px = (xw + 0.5f) + op[1] - 0.5f;
    float py = (y + 0.5f) + op[2] - 0.5f;
    float d0f = floorf(pd), x0f = floorf(px), y0f = floorf(py);
    float fd = pd - d0f, fx = px - x0f, fy = py - y0f;
    int di = (int)d0f + dd, yi = (int)y0f + dy, xi = (int)x0f + dx;
    bool inb = (di >= 0) & (di < SS) & (yi >= 0) & (yi < HH) & (xi >= 0) & (xi < WW);
    float wgt = (dd ? fd : 1.f - fd) * (dy ? fy : 1.f - fy) * (dx ? fx : 1.f - fx) * awp;
    wgt = inb ? wgt : 0.f;
    int dic = min(max(di, 0), SS - 1);
    int yic = min(max(yi, 0), HH - 1);
    int xic = min(max(xi, 0), WW - 1);
    int bo = (((dic * HH) + yic) * WW + xic) * (HD * 2);

    cw[gl][j] = make_uint2((unsigned)bo, __float_as_uint(wgt));
    __syncthreads();

    const char* vhead = (const char*)(vbuf + ((size_t)(b * NH + h) * LL) * HD) + 2 * j;
    const uint4* cw4 = reinterpret_cast<const uint4*>(&cw[gl][0]);
    float acc = 0.f;
#pragma unroll
    for (int q = 0; q < 16; ++q) {
        uint4 c = cw4[q];     // uniform address per 32-lane group -> broadcast
        u16 v0 = *reinterpret_cast<const u16*>(vhead + c.x);
        u16 v1 = *reinterpret_cast<const u16*>(vhead + c.z);
        acc += __uint_as_float(c.y) * __uint_as_float(((unsigned)v0) << 16);
        acc += __uint_as_float(c.w) * __uint_as_float(((unsigned)v1) << 16);
    }
    dout[(size_t)(b * LL + l) * CC + h * HD + j] = f2b(acc);
}

// ---------------------------------------------------------------------------
// LayerNorm over C=192, one wave per row; bf16 output (fc1 input).
// ---------------------------------------------------------------------------
__global__ __launch_bounds__(256) void layernorm_kernel(const float* __restrict__ hin,
                                                        const float* __restrict__ g2,
                                                        const float* __restrict__ b2,
                                                        u16* __restrict__ lnout) {
    int row = blockIdx.x * 4 + (threadIdx.x >> 6);
    int lane = threadIdx.x & 63;
    const float* hr = hin + (size_t)row * CC;
    float v0 = hr[lane], v1 = hr[lane + 64], v2 = hr[lane + 128];
    float s = v0 + v1 + v2;
    float sq = v0 * v0 + v1 * v1 + v2 * v2;
#pragma unroll
    for (int o = 32; o > 0; o >>= 1) {
        s += __shfl_xor(s, o);
        sq += __shfl_xor(sq, o);
    }
    float m = s * (1.0f / CC);
    float var = sq * (1.0f / CC) - m * m;
    float r = rsqrtf(var + 1e-5f);
    u16* lo = lnout + (size_t)row * CC;
    lo[lane]       = f2b((v0 - m) * r * g2[lane]       + b2[lane]);
    lo[lane + 64]  = f2b((v1 - m) * r * g2[lane + 64]  + b2[lane + 64]);
    lo[lane + 128] = f2b((v2 - m) * r * g2[lane + 128] + b2[lane + 128]);
}

// ---------------------------------------------------------------------------
extern "C" void kernel_launch(void* const* d_in, const int* in_sizes, int n_in,
                              void* d_out, int out_size, void* d_ws, size_t ws_size,
                              hipStream_t stream) {
    const float* x    = (const float*)d_in[0];
    const float* Wv   = (const float*)d_in[2];
    const float* bv   = (const float*)d_in[3];
    const float* Woff = (const float*)d_in[4];
    const float* boff = (const float*)d_in[5];
    const float* Waw  = (const float*)d_in[6];
    const float* baw  = (const float*)d_in[7];
    const float* Wout = (const float*)d_in[8];
    const float* bout = (const float*)d_in[9];
    const float* g2   = (const float*)d_in[10];
    const float* b2   = (const float*)d_in[11];
    const float* W1   = (const float*)d_in[12];
    const float* b1   = (const float*)d_in[13];
    const float* W2   = (const float*)d_in[14];
    const float* b2m  = (const float*)d_in[15];

    char* wsb = (char*)d_ws;
    u16*   xp    = (u16*)(wsb + 0);              // [0, 12.6M)
    u16*   vbuf  = (u16*)(wsb + 12582912);       // [12.6M, 25.2M)
    float* offaw = (float*)(wsb + 25165824);     // [25.2M, 37.8M)
    u16*   dbuf  = (u16*)(wsb + 0);              // reuses xp (dead after proj gemm)
    u16*   hid   = (u16*)(wsb + 12582912);       // reuses vbuf+offaw (dead after deform)
    float* hbuf  = (float*)(wsb + 66060288);
    u16*   ln    = (u16*)(wsb + 92274688);
    u16*   wcatT = (u16*)(wsb + 105906176);
    u16*   woutT = wcatT + NPROJ * CC;
    u16*   w1T   = woutT + CC * CC;
    u16*   w2T   = w1T + HID * CC;
    float* bcat  = (float*)(w2T + CC * HID);
    float* out   = (float*)d_out;

    int wtot = NPROJ * CC + CC * CC + HID * CC + CC * HID + NPROJ;
    build_weights<<<(wtot + 255) / 256, 256, 0, stream>>>(
        Wv, Woff, Waw, Wout, W1, W2, bv, boff, baw, wcatT, woutT, w1T, w2T, bcat);
    transpose_in<<<dim3(LL / 32, CC / 32, BB), dim3(32, 8), 0, stream>>>(x, xp);
    gemm_mfma<0><<<dim3(2, MTOK / 128), 256, 0, stream>>>(
        xp, wcatT, bcat, nullptr, vbuf, offaw, MTOK, NPROJ, CC);
    deform_kernel<<<(BB * LL * NH) / 8, 256, 0, stream>>>(vbuf, offaw, dbuf);
    gemm_mfma<1><<<dim3(1, MTOK / 128), 256, 0, stream>>>(
        dbuf, woutT, bout, x /* shortcut view */, hbuf, nullptr, MTOK, CC, CC);
    layernorm_kernel<<<MTOK / 4, 256, 0, stream>>>(hbuf, g2, b2, ln);
    gemm_mfma<2><<<dim3(4, MTOK / 128), 256, 0, stream>>>(
        ln, w1T, b1, nullptr, hid, nullptr, MTOK, HID, CC);
    gemm_mfma<3><<<dim3(1, MTOK / 128), 256, 0, stream>>>(
        hid, w2T, b2m, hbuf, out, nullptr, MTOK, CC, HID);
}

// Round 8
// 265.181 us; speedup vs baseline: 3.2404x; 1.0736x over previous
//
#include <hip/hip_runtime.h>
#include <hip/hip_bf16.h>
#include <math.h>

// Problem constants
#define BB 2
#define CC 192
#define SS 16
#define HH 32
#define WW 32
#define NH 6
#define PP 4
#define HD 32
#define HID 768
#define LL (SS * HH * WW)        // 16384
#define MTOK (BB * LL)           // 32768 tokens
#define NPROJ 288                // 192 (value) + 72 (off) + 24 (aw)

typedef unsigned short u16;
typedef u16 u16x8 __attribute__((ext_vector_type(8)));
typedef __bf16 bf16x8 __attribute__((ext_vector_type(8)));
typedef float f32x4 __attribute__((ext_vector_type(4)));

static __device__ __forceinline__ u16 f2b(float f) {
    __hip_bfloat16 h = __float2bfloat16(f);
    return *reinterpret_cast<u16*>(&h);
}

// fast GELU: v * sigmoid(1.5957691(v + 0.044715 v^3)); |err| ~1e-3 << bf16 ulp here
static __device__ __forceinline__ float fast_gelu(float v) {
    float z = 1.5957691216057308f * (v + 0.044715f * v * v * v);
    return v * __builtin_amdgcn_rcpf(1.0f + __expf(-z));
}

// ---------------------------------------------------------------------------
// Build all bf16 transposed weights (N x K layout) + concatenated bias (fp32)
// ---------------------------------------------------------------------------
__global__ void build_weights(const float* __restrict__ Wv, const float* __restrict__ Woff,
                              const float* __restrict__ Waw, const float* __restrict__ Wout,
                              const float* __restrict__ W1, const float* __restrict__ W2,
                              const float* __restrict__ bv, const float* __restrict__ boff,
                              const float* __restrict__ baw,
                              u16* __restrict__ wcatT, u16* __restrict__ woutT,
                              u16* __restrict__ w1T, u16* __restrict__ w2T,
                              float* __restrict__ bcat) {
    int i = blockIdx.x * 256 + threadIdx.x;
    if (i < NPROJ * CC) {                       // wcatT[n][k] = Wcat[k][n]
        int n = i / CC, k = i % CC;
        float v = (n < 192) ? Wv[k * 192 + n]
                : (n < 264) ? Woff[k * 72 + (n - 192)]
                            : Waw[k * 24 + (n - 264)];
        wcatT[i] = f2b(v);
        return;
    }
    i -= NPROJ * CC;
    if (i < CC * CC) {
        int n = i / CC, k = i % CC;
        woutT[i] = f2b(Wout[k * CC + n]);
        return;
    }
    i -= CC * CC;
    if (i < HID * CC) {
        int n = i / CC, k = i % CC;
        w1T[i] = f2b(W1[k * HID + n]);
        return;
    }
    i -= HID * CC;
    if (i < CC * HID) {
        int n = i / HID, k = i % HID;
        w2T[i] = f2b(W2[k * CC + n]);
        return;
    }
    i -= CC * HID;
    if (i < NPROJ) {
        float v = (i < 192) ? bv[i] : (i < 264) ? boff[i - 192] : baw[i - 264];
        bcat[i] = v;
    }
}

// ---------------------------------------------------------------------------
// x (B, C, L) channel-major  ->  xp (B, L, C) token-major bf16
// ---------------------------------------------------------------------------
__global__ void transpose_in(const float* __restrict__ x, u16* __restrict__ xp) {
    __shared__ float s[32][33];
    int b = blockIdx.z;
    int c0 = blockIdx.y * 32;
    int l0 = blockIdx.x * 32;
    int tx = threadIdx.x, ty = threadIdx.y;
#pragma unroll
    for (int r = 0; r < 32; r += 8)
        s[ty + r][tx] = x[((size_t)b * CC + c0 + ty + r) * LL + l0 + tx];
    __syncthreads();
#pragma unroll
    for (int r = 0; r < 32; r += 8)
        xp[((size_t)b * LL + l0 + ty + r) * CC + c0 + tx] = f2b(s[tx][ty + r]);
}

// ---------------------------------------------------------------------------
// MFMA bf16 GEMM: C(MxN) = A(MxK) @ Bt(NxK)^T + bias.  BM=128, BN=32*NF.
// 256 threads = 4 waves (2x2), wave tile 64 x (16*NF).
// For EPI 0/1/2 operands are SWAPPED (mfma(b,a)): acc regs hold 4 consecutive
// n, lanes hold m -> packed wide stores + float4 bias/add loads.
// EPI: 0 = split: n<192 -> vbuf bf16 (B,NH,L,HD); n>=192 -> offaw fp32 (M,96)
//      1 = fp32 out + bias + add       (wout + shortcut), token-major
//      2 = bf16 out fast_gelu(acc+bias) (fc1), token-major
//      3 = fp32 out + bias + add, CHANNEL-MAJOR (B,C,L)  (fc2 + residual),
//          operands NOT swapped (m in regs -> float4 along l).
// ---------------------------------------------------------------------------
template<int EPI, int NF>
__global__ __launch_bounds__(256, 2) void gemm_mfma(const u16* __restrict__ A,
                                                    const u16* __restrict__ Bt,
                                                    const float* __restrict__ bias,
                                                    const float* __restrict__ add,
                                                    void* __restrict__ Cout,
                                                    void* __restrict__ Cout2,
                                                    int M, int N, int K) {
    constexpr int BN = NF * 32;
    __shared__ u16 As[128][40];
    __shared__ u16 Bs[BN][40];
    int t = threadIdx.x;
    int m0 = blockIdx.y * 128;
    int n0 = blockIdx.x * BN;
    int w = t >> 6, lane = t & 63;
    int wm = w >> 1, wn = w & 1;
    int lrow = lane & 15, q = lane >> 4;
    int lk8 = q * 8;

    f32x4 acc[4][NF];
#pragma unroll
    for (int i = 0; i < 4; ++i)
#pragma unroll
        for (int f = 0; f < NF; ++f)
#pragma unroll
            for (int r = 0; r < 4; ++r) acc[i][f][r] = 0.f;

    int arow = t >> 2, aseg = (t & 3) * 8;

    for (int k0 = 0; k0 < K; k0 += 32) {
        *reinterpret_cast<u16x8*>(&As[arow][aseg]) =
            *reinterpret_cast<const u16x8*>(A + (size_t)(m0 + arow) * K + k0 + aseg);
        *reinterpret_cast<u16x8*>(&As[arow + 64][aseg]) =
            *reinterpret_cast<const u16x8*>(A + (size_t)(m0 + arow + 64) * K + k0 + aseg);
#pragma unroll
        for (int idx = 0; idx < BN * 4; idx += 256) {
            int ii = idx + t;
            if (ii < BN * 4) {
                int br = ii >> 2, bseg = (ii & 3) * 8;
                *reinterpret_cast<u16x8*>(&Bs[br][bseg]) =
                    *reinterpret_cast<const u16x8*>(Bt + (size_t)(n0 + br) * K + k0 + bseg);
            }
        }
        __syncthreads();
        bf16x8 af[4], bfr[NF];
#pragma unroll
        for (int i = 0; i < 4; ++i)
            af[i] = *reinterpret_cast<const bf16x8*>(&As[wm * 64 + i * 16 + lrow][lk8]);
#pragma unroll
        for (int f = 0; f < NF; ++f)
            bfr[f] = *reinterpret_cast<const bf16x8*>(&Bs[wn * (16 * NF) + f * 16 + lrow][lk8]);
#pragma unroll
        for (int i = 0; i < 4; ++i)
#pragma unroll
            for (int f = 0; f < NF; ++f) {
                if (EPI == 3)
                    acc[i][f] = __builtin_amdgcn_mfma_f32_16x16x32_bf16(af[i], bfr[f], acc[i][f], 0, 0, 0);
                else
                    acc[i][f] = __builtin_amdgcn_mfma_f32_16x16x32_bf16(bfr[f], af[i], acc[i][f], 0, 0, 0);
            }
        __syncthreads();
    }

    if (EPI == 3) {
        // m in regs: channel-major float4 along l
#pragma unroll
        for (int i = 0; i < 4; ++i) {
#pragma unroll
            for (int f = 0; f < NF; ++f) {
                int n = n0 + wn * (16 * NF) + f * 16 + lrow;
                float bvn = bias[n];
                int mb = m0 + wm * 64 + i * 16 + q * 4;
                float4 vv;
#pragma unroll
                for (int r = 0; r < 4; ++r)
                    ((float*)&vv)[r] = acc[i][f][r] + bvn + add[(size_t)(mb + r) * N + n];
                int b = mb >> 14, l = mb & (LL - 1);
                *reinterpret_cast<float4*>((float*)Cout + ((size_t)b * CC + n) * LL + l) = vv;
            }
        }
    } else {
        // swapped: n in regs (4 consecutive), m on lanes
#pragma unroll
        for (int i = 0; i < 4; ++i) {
            int m = m0 + wm * 64 + i * 16 + lrow;
#pragma unroll
            for (int f = 0; f < NF; ++f) {
                int nq = n0 + wn * (16 * NF) + f * 16 + q * 4;
                float4 bias4 = *reinterpret_cast<const float4*>(bias + nq);
                if (EPI == 0) {
                    if (nq < 192) {
                        int h = nq >> 5, hd = nq & 31;
                        int b = m >> 14, l = m & (LL - 1);
                        u16 p0 = f2b(acc[i][f][0] + bias4.x);
                        u16 p1 = f2b(acc[i][f][1] + bias4.y);
                        u16 p2 = f2b(acc[i][f][2] + bias4.z);
                        u16 p3 = f2b(acc[i][f][3] + bias4.w);
                        uint2 pk = make_uint2((unsigned)p0 | ((unsigned)p1 << 16),
                                              (unsigned)p2 | ((unsigned)p3 << 16));
                        *reinterpret_cast<uint2*>(
                            (u16*)Cout + (((size_t)b * NH + h) * LL + l) * HD + hd) = pk;
                    } else {
                        float4 vv;
                        vv.x = acc[i][f][0] + bias4.x;
                        vv.y = acc[i][f][1] + bias4.y;
                        vv.z = acc[i][f][2] + bias4.z;
                        vv.w = acc[i][f][3] + bias4.w;
                        *reinterpret_cast<float4*>((float*)Cout2 + (size_t)m * 96 + (nq - 192)) = vv;
                    }
                } else if (EPI == 1) {
                    float4 add4 = *reinterpret_cast<const float4*>(add + (size_t)m * N + nq);
                    float4 vv;
                    vv.x = acc[i][f][0] + bias4.x + add4.x;
                    vv.y = acc[i][f][1] + bias4.y + add4.y;
                    vv.z = acc[i][f][2] + bias4.z + add4.z;
                    vv.w = acc[i][f][3] + bias4.w + add4.w;
                    *reinterpret_cast<float4*>((float*)Cout + (size_t)m * N + nq) = vv;
                } else { // EPI == 2
                    u16 p0 = f2b(fast_gelu(acc[i][f][0] + bias4.x));
                    u16 p1 = f2b(fast_gelu(acc[i][f][1] + bias4.y));
                    u16 p2 = f2b(fast_gelu(acc[i][f][2] + bias4.z));
                    u16 p3 = f2b(fast_gelu(acc[i][f][3] + bias4.w));
                    uint2 pk = make_uint2((unsigned)p0 | ((unsigned)p1 << 16),
                                          (unsigned)p2 | ((unsigned)p3 << 16));
                    *reinterpret_cast<uint2*>((u16*)Cout + (size_t)m * N + nq) = pk;
                }
            }
        }
    }
}

// ---------------------------------------------------------------------------
// Deformable sampling, LDS-broadcast version (round-5 structure).
// ---------------------------------------------------------------------------
__global__ __launch_bounds__(256) void deform_kernel(const u16* __restrict__ vbuf,
                                                     const float* __restrict__ offaw,
                                                     u16* __restrict__ dout) {
    __shared__ uint2 cw[8][32];
    int gl = threadIdx.x >> 5;
    int g = blockIdx.x * 8 + gl;
    int j = threadIdx.x & 31;
    int h = g % NH;
    int tmp = g / NH;
    int l = tmp % LL;
    int b = tmp / LL;
    int d = l >> 10, rem = l & 1023, y = rem >> 5, xw = rem & 31;

    const float* oa = offaw + (size_t)(b * LL + l) * 96;
    int p = j >> 3, cor = j & 7;
    int dx = cor & 1, dy = (cor >> 1) & 1, dd = cor >> 2;

    float4 lg = *reinterpret_cast<const float4*>(oa + 72 + h * 4);
    float mx = fmaxf(fmaxf(lg.x, lg.y), fmaxf(lg.z, lg.w));
    float e0 = __expf(lg.x - mx), e1 = __expf(lg.y - mx);
    float e2 = __expf(lg.z - mx), e3 = __expf(lg.w - mx);
    float inv = __builtin_amdgcn_rcpf(e0 + e1 + e2 + e3);
    float ep = (p == 0) ? e0 : (p == 1) ? e1 : (p == 2) ? e2 : e3;
    float awp = ep * inv;

    const float* op = oa + (h * 4 + p) * 3;
    float pd = (d + 0.5f) + op[0] - 0.5f;
    float px = (xw + 0.5f) + op[1] - 0.5f;
    float py = (y + 0.5f) + op[2] - 0.5f;
    float d0f = floorf(pd), x0f = floorf(px), y0f = floorf(py);
    float fd = pd - d0f, fx = px - x0f, fy = py - y0f;
    int di = (int)d0f + dd, yi = (int)y0f + dy, xi = (int)x0f + dx;
    bool inb = (di >= 0) & (di < SS) & (yi >= 0) & (yi < HH) & (xi >= 0) & (xi < WW);
    float wgt = (dd ? fd : 1.f - fd) * (dy ? fy : 1.f - fy) * (dx ? fx : 1.f - fx) * awp;
    wgt = inb ? wgt : 0.f;
    int dic = min(max(di, 0), SS - 1);
    int yic = min(max(yi, 0), HH - 1);
    int xic = min(max(xi, 0), WW - 1);
    int bo = (((dic * HH) + yic) * WW + xic) * (HD * 2);

    cw[gl][j] = make_uint2((unsigned)bo, __float_as_uint(wgt));
    __syncthreads();

    const char* vhead = (const char*)(vbuf + ((size_t)(b * NH + h) * LL) * HD) + 2 * j;
    const uint4* cw4 = reinterpret_cast<const uint4*>(&cw[gl][0]);
    float acc = 0.f;
#pragma unroll
    for (int qq = 0; qq < 16; ++qq) {
        uint4 c = cw4[qq];    // uniform address per 32-lane group -> broadcast
        u16 v0 = *reinterpret_cast<const u16*>(vhead + c.x);
        u16 v1 = *reinterpret_cast<const u16*>(vhead + c.z);
        acc += __uint_as_float(c.y) * __uint_as_float(((unsigned)v0) << 16);
        acc += __uint_as_float(c.w) * __uint_as_float(((unsigned)v1) << 16);
    }
    dout[(size_t)(b * LL + l) * CC + h * HD + j] = f2b(acc);
}

// ---------------------------------------------------------------------------
// LayerNorm over C=192, one wave per row; bf16 output (fc1 input).
// ---------------------------------------------------------------------------
__global__ __launch_bounds__(256) void layernorm_kernel(const float* __restrict__ hin,
                                                        const float* __restrict__ g2,
                                                        const float* __restrict__ b2,
                                                        u16* __restrict__ lnout) {
    int row = blockIdx.x * 4 + (threadIdx.x >> 6);
    int lane = threadIdx.x & 63;
    const float* hr = hin + (size_t)row * CC;
    float v0 = hr[lane], v1 = hr[lane + 64], v2 = hr[lane + 128];
    float s = v0 + v1 + v2;
    float sq = v0 * v0 + v1 * v1 + v2 * v2;
#pragma unroll
    for (int o = 32; o > 0; o >>= 1) {
        s += __shfl_xor(s, o);
        sq += __shfl_xor(sq, o);
    }
    float m = s * (1.0f / CC);
    float var = sq * (1.0f / CC) - m * m;
    float r = rsqrtf(var + 1e-5f);
    u16* lo = lnout + (size_t)row * CC;
    lo[lane]       = f2b((v0 - m) * r * g2[lane]       + b2[lane]);
    lo[lane + 64]  = f2b((v1 - m) * r * g2[lane + 64]  + b2[lane + 64]);
    lo[lane + 128] = f2b((v2 - m) * r * g2[lane + 128] + b2[lane + 128]);
}

// ---------------------------------------------------------------------------
extern "C" void kernel_launch(void* const* d_in, const int* in_sizes, int n_in,
                              void* d_out, int out_size, void* d_ws, size_t ws_size,
                              hipStream_t stream) {
    const float* x    = (const float*)d_in[0];
    const float* Wv   = (const float*)d_in[2];
    const float* bv   = (const float*)d_in[3];
    const float* Woff = (const float*)d_in[4];
    const float* boff = (const float*)d_in[5];
    const float* Waw  = (const float*)d_in[6];
    const float* baw  = (const float*)d_in[7];
    const float* Wout = (const float*)d_in[8];
    const float* bout = (const float*)d_in[9];
    const float* g2   = (const float*)d_in[10];
    const float* b2   = (const float*)d_in[11];
    const float* W1   = (const float*)d_in[12];
    const float* b1   = (const float*)d_in[13];
    const float* W2   = (const float*)d_in[14];
    const float* b2m  = (const float*)d_in[15];

    char* wsb = (char*)d_ws;
    u16*   xp    = (u16*)(wsb + 0);              // [0, 12.6M)
    u16*   vbuf  = (u16*)(wsb + 12582912);       // [12.6M, 25.2M)
    float* offaw = (float*)(wsb + 25165824);     // [25.2M, 37.8M)
    u16*   dbuf  = (u16*)(wsb + 0);              // reuses xp (dead after proj gemm)
    u16*   hid   = (u16*)(wsb + 12582912);       // reuses vbuf+offaw (dead after deform)
    float* hbuf  = (float*)(wsb + 66060288);
    u16*   ln    = (u16*)(wsb + 92274688);
    u16*   wcatT = (u16*)(wsb + 105906176);
    u16*   woutT = wcatT + NPROJ * CC;
    u16*   w1T   = woutT + CC * CC;
    u16*   w2T   = w1T + HID * CC;
    float* bcat  = (float*)(w2T + CC * HID);
    float* out   = (float*)d_out;

    int wtot = NPROJ * CC + CC * CC + HID * CC + CC * HID + NPROJ;
    build_weights<<<(wtot + 255) / 256, 256, 0, stream>>>(
        Wv, Woff, Waw, Wout, W1, W2, bv, boff, baw, wcatT, woutT, w1T, w2T, bcat);
    transpose_in<<<dim3(LL / 32, CC / 32, BB), dim3(32, 8), 0, stream>>>(x, xp);
    gemm_mfma<0, 3><<<dim3(3, MTOK / 128), 256, 0, stream>>>(
        xp, wcatT, bcat, nullptr, vbuf, offaw, MTOK, NPROJ, CC);
    deform_kernel<<<(BB * LL * NH) / 8, 256, 0, stream>>>(vbuf, offaw, dbuf);
    gemm_mfma<1, 3><<<dim3(2, MTOK / 128), 256, 0, stream>>>(
        dbuf, woutT, bout, x /* shortcut view */, hbuf, nullptr, MTOK, CC, CC);
    layernorm_kernel<<<MTOK / 4, 256, 0, stream>>>(hbuf, g2, b2, ln);
    gemm_mfma<2, 6><<<dim3(4, MTOK / 128), 256, 0, stream>>>(
        ln, w1T, b1, nullptr, hid, nullptr, MTOK, HID, CC);
    gemm_mfma<3, 3><<<dim3(2, MTOK / 128), 256, 0, stream>>>(
        hid, w2T, b2m, hbuf, out, nullptr, MTOK, CC, HID);
}

// Round 9
// 228.007 us; speedup vs baseline: 3.7688x; 1.1630x over previous
//
#include <hip/hip_runtime.h>
#include <hip/hip_bf16.h>
#include <math.h>

// Problem constants
#define BB 2
#define CC 192
#define SS 16
#define HH 32
#define WW 32
#define NH 6
#define PP 4
#define HD 32
#define HID 768
#define LL (SS * HH * WW)        // 16384
#define MTOK (BB * LL)           // 32768 tokens
#define NPROJ 288                // 192 (value) + 72 (off) + 24 (aw)

typedef unsigned short u16;
typedef u16 u16x8 __attribute__((ext_vector_type(8)));
typedef __bf16 bf16x8 __attribute__((ext_vector_type(8)));
typedef float f32x4 __attribute__((ext_vector_type(4)));

static __device__ __forceinline__ u16 f2b(float f) {
    __hip_bfloat16 h = __float2bfloat16(f);
    return *reinterpret_cast<u16*>(&h);
}

// fast GELU: v * sigmoid(1.5957691(v + 0.044715 v^3)); |err| ~1e-3 << bf16 ulp here
static __device__ __forceinline__ float fast_gelu(float v) {
    float z = 1.5957691216057308f * (v + 0.044715f * v * v * v);
    return v * __builtin_amdgcn_rcpf(1.0f + __expf(-z));
}

// ---------------------------------------------------------------------------
// Build all bf16 transposed weights (N x K layout) + concatenated bias (fp32)
// ---------------------------------------------------------------------------
__global__ void build_weights(const float* __restrict__ Wv, const float* __restrict__ Woff,
                              const float* __restrict__ Waw, const float* __restrict__ Wout,
                              const float* __restrict__ W1, const float* __restrict__ W2,
                              const float* __restrict__ bv, const float* __restrict__ boff,
                              const float* __restrict__ baw,
                              u16* __restrict__ wcatT, u16* __restrict__ woutT,
                              u16* __restrict__ w1T, u16* __restrict__ w2T,
                              float* __restrict__ bcat) {
    int i = blockIdx.x * 256 + threadIdx.x;
    if (i < NPROJ * CC) {                       // wcatT[n][k] = Wcat[k][n]
        int n = i / CC, k = i % CC;
        float v = (n < 192) ? Wv[k * 192 + n]
                : (n < 264) ? Woff[k * 72 + (n - 192)]
                            : Waw[k * 24 + (n - 264)];
        wcatT[i] = f2b(v);
        return;
    }
    i -= NPROJ * CC;
    if (i < CC * CC) {
        int n = i / CC, k = i % CC;
        woutT[i] = f2b(Wout[k * CC + n]);
        return;
    }
    i -= CC * CC;
    if (i < HID * CC) {
        int n = i / CC, k = i % CC;
        w1T[i] = f2b(W1[k * HID + n]);
        return;
    }
    i -= HID * CC;
    if (i < CC * HID) {
        int n = i / HID, k = i % HID;
        w2T[i] = f2b(W2[k * CC + n]);
        return;
    }
    i -= CC * HID;
    if (i < NPROJ) {
        float v = (i < 192) ? bv[i] : (i < 264) ? boff[i - 192] : baw[i - 264];
        bcat[i] = v;
    }
}

// ---------------------------------------------------------------------------
// x (B, C, L) channel-major  ->  xp (B, L, C) token-major bf16
// ---------------------------------------------------------------------------
__global__ void transpose_in(const float* __restrict__ x, u16* __restrict__ xp) {
    __shared__ float s[32][33];
    int b = blockIdx.z;
    int c0 = blockIdx.y * 32;
    int l0 = blockIdx.x * 32;
    int tx = threadIdx.x, ty = threadIdx.y;
#pragma unroll
    for (int r = 0; r < 32; r += 8)
        s[ty + r][tx] = x[((size_t)b * CC + c0 + ty + r) * LL + l0 + tx];
    __syncthreads();
#pragma unroll
    for (int r = 0; r < 32; r += 8)
        xp[((size_t)b * LL + l0 + ty + r) * CC + c0 + tx] = f2b(s[tx][ty + r]);
}

// ---------------------------------------------------------------------------
// MFMA bf16 GEMM: C(MxN) = A(MxK) @ Bt(NxK)^T + bias.  BM=128, BN=32*NF.
// 256 threads = 4 waves (2x2), wave tile 64 x (16*NF).
// Double-buffered LDS, ONE barrier per K-step: prefetch k+1 into regs,
// compute k from LDS[cur], ds_write regs to LDS[cur^1], barrier.
// For EPI 0/1/2 operands are SWAPPED (mfma(b,a)): acc regs hold 4 consecutive
// n, lanes hold m -> packed wide stores + float4 bias/add loads.
// EPI: 0 = split: n<192 -> vbuf bf16 (B,NH,L,HD); n>=192 -> offaw fp32 (M,96)
//      1 = fp32 out + bias + add       (wout + shortcut), token-major
//      2 = bf16 out fast_gelu(acc+bias) (fc1), token-major
//      3 = fp32 out + bias + add, CHANNEL-MAJOR (B,C,L)  (fc2 + residual),
//          operands NOT swapped (m in regs -> float4 along l).
// ---------------------------------------------------------------------------
template<int EPI, int NF>
__global__ __launch_bounds__(256, 2) void gemm_mfma(const u16* __restrict__ A,
                                                    const u16* __restrict__ Bt,
                                                    const float* __restrict__ bias,
                                                    const float* __restrict__ add,
                                                    void* __restrict__ Cout,
                                                    void* __restrict__ Cout2,
                                                    int M, int N, int K) {
    constexpr int BN = NF * 32;
    constexpr int NB = (BN * 4 + 255) / 256;   // B-load slots per thread
    __shared__ u16 As[2][128][40];
    __shared__ u16 Bs[2][BN][40];
    int t = threadIdx.x;
    int m0 = blockIdx.y * 128;
    int n0 = blockIdx.x * BN;
    int w = t >> 6, lane = t & 63;
    int wm = w >> 1, wn = w & 1;
    int lrow = lane & 15, q = lane >> 4;
    int lk8 = q * 8;

    f32x4 acc[4][NF];
#pragma unroll
    for (int i = 0; i < 4; ++i)
#pragma unroll
        for (int f = 0; f < NF; ++f)
#pragma unroll
            for (int r = 0; r < 4; ++r) acc[i][f][r] = 0.f;

    int arow = t >> 2, aseg = (t & 3) * 8;
    const u16* Arow0 = A + (size_t)(m0 + arow) * K + aseg;
    const u16* Arow1 = A + (size_t)(m0 + arow + 64) * K + aseg;

    u16x8 av0, av1, bv[NB];
    // ---- prologue: stage k-tile 0 into buffer 0
    av0 = *reinterpret_cast<const u16x8*>(Arow0);
    av1 = *reinterpret_cast<const u16x8*>(Arow1);
#pragma unroll
    for (int u2 = 0; u2 < NB; ++u2) {
        int ii = t + u2 * 256;
        if (ii < BN * 4) {
            int br = ii >> 2, bseg = (ii & 3) * 8;
            bv[u2] = *reinterpret_cast<const u16x8*>(Bt + (size_t)(n0 + br) * K + bseg);
        }
    }
    *reinterpret_cast<u16x8*>(&As[0][arow][aseg]) = av0;
    *reinterpret_cast<u16x8*>(&As[0][arow + 64][aseg]) = av1;
#pragma unroll
    for (int u2 = 0; u2 < NB; ++u2) {
        int ii = t + u2 * 256;
        if (ii < BN * 4) {
            int br = ii >> 2, bseg = (ii & 3) * 8;
            *reinterpret_cast<u16x8*>(&Bs[0][br][bseg]) = bv[u2];
        }
    }
    __syncthreads();

    int NT = K >> 5;
    int cur = 0;
    for (int ti = 0; ti < NT - 1; ++ti) {
        int k1 = (ti + 1) << 5;
        // prefetch next k-tile into registers (overlaps with compute below)
        av0 = *reinterpret_cast<const u16x8*>(Arow0 + k1);
        av1 = *reinterpret_cast<const u16x8*>(Arow1 + k1);
#pragma unroll
        for (int u2 = 0; u2 < NB; ++u2) {
            int ii = t + u2 * 256;
            if (ii < BN * 4) {
                int br = ii >> 2, bseg = (ii & 3) * 8;
                bv[u2] = *reinterpret_cast<const u16x8*>(Bt + (size_t)(n0 + br) * K + k1 + bseg);
            }
        }
        // compute current k-tile
        {
            bf16x8 af[4], bfr[NF];
#pragma unroll
            for (int i = 0; i < 4; ++i)
                af[i] = *reinterpret_cast<const bf16x8*>(&As[cur][wm * 64 + i * 16 + lrow][lk8]);
#pragma unroll
            for (int f = 0; f < NF; ++f)
                bfr[f] = *reinterpret_cast<const bf16x8*>(&Bs[cur][wn * (16 * NF) + f * 16 + lrow][lk8]);
#pragma unroll
            for (int i = 0; i < 4; ++i)
#pragma unroll
                for (int f = 0; f < NF; ++f) {
                    if (EPI == 3)
                        acc[i][f] = __builtin_amdgcn_mfma_f32_16x16x32_bf16(af[i], bfr[f], acc[i][f], 0, 0, 0);
                    else
                        acc[i][f] = __builtin_amdgcn_mfma_f32_16x16x32_bf16(bfr[f], af[i], acc[i][f], 0, 0, 0);
                }
        }
        // write prefetched tile to the other buffer; single barrier
        *reinterpret_cast<u16x8*>(&As[cur ^ 1][arow][aseg]) = av0;
        *reinterpret_cast<u16x8*>(&As[cur ^ 1][arow + 64][aseg]) = av1;
#pragma unroll
        for (int u2 = 0; u2 < NB; ++u2) {
            int ii = t + u2 * 256;
            if (ii < BN * 4) {
                int br = ii >> 2, bseg = (ii & 3) * 8;
                *reinterpret_cast<u16x8*>(&Bs[cur ^ 1][br][bseg]) = bv[u2];
            }
        }
        __syncthreads();
        cur ^= 1;
    }
    // last k-tile (no prefetch)
    {
        bf16x8 af[4], bfr[NF];
#pragma unroll
        for (int i = 0; i < 4; ++i)
            af[i] = *reinterpret_cast<const bf16x8*>(&As[cur][wm * 64 + i * 16 + lrow][lk8]);
#pragma unroll
        for (int f = 0; f < NF; ++f)
            bfr[f] = *reinterpret_cast<const bf16x8*>(&Bs[cur][wn * (16 * NF) + f * 16 + lrow][lk8]);
#pragma unroll
        for (int i = 0; i < 4; ++i)
#pragma unroll
            for (int f = 0; f < NF; ++f) {
                if (EPI == 3)
                    acc[i][f] = __builtin_amdgcn_mfma_f32_16x16x32_bf16(af[i], bfr[f], acc[i][f], 0, 0, 0);
                else
                    acc[i][f] = __builtin_amdgcn_mfma_f32_16x16x32_bf16(bfr[f], af[i], acc[i][f], 0, 0, 0);
            }
    }

    if (EPI == 3) {
        // m in regs: channel-major float4 along l
#pragma unroll
        for (int i = 0; i < 4; ++i) {
#pragma unroll
            for (int f = 0; f < NF; ++f) {
                int n = n0 + wn * (16 * NF) + f * 16 + lrow;
                float bvn = bias[n];
                int mb = m0 + wm * 64 + i * 16 + q * 4;
                float4 vv;
#pragma unroll
                for (int r = 0; r < 4; ++r)
                    ((float*)&vv)[r] = acc[i][f][r] + bvn + add[(size_t)(mb + r) * N + n];
                int b = mb >> 14, l = mb & (LL - 1);
                *reinterpret_cast<float4*>((float*)Cout + ((size_t)b * CC + n) * LL + l) = vv;
            }
        }
    } else {
        // swapped: n in regs (4 consecutive), m on lanes
#pragma unroll
        for (int i = 0; i < 4; ++i) {
            int m = m0 + wm * 64 + i * 16 + lrow;
#pragma unroll
            for (int f = 0; f < NF; ++f) {
                int nq = n0 + wn * (16 * NF) + f * 16 + q * 4;
                float4 bias4 = *reinterpret_cast<const float4*>(bias + nq);
                if (EPI == 0) {
                    if (nq < 192) {
                        int h = nq >> 5, hd = nq & 31;
                        int b = m >> 14, l = m & (LL - 1);
                        u16 p0 = f2b(acc[i][f][0] + bias4.x);
                        u16 p1 = f2b(acc[i][f][1] + bias4.y);
                        u16 p2 = f2b(acc[i][f][2] + bias4.z);
                        u16 p3 = f2b(acc[i][f][3] + bias4.w);
                        uint2 pk = make_uint2((unsigned)p0 | ((unsigned)p1 << 16),
                                              (unsigned)p2 | ((unsigned)p3 << 16));
                        *reinterpret_cast<uint2*>(
                            (u16*)Cout + (((size_t)b * NH + h) * LL + l) * HD + hd) = pk;
                    } else {
                        float4 vv;
                        vv.x = acc[i][f][0] + bias4.x;
                        vv.y = acc[i][f][1] + bias4.y;
                        vv.z = acc[i][f][2] + bias4.z;
                        vv.w = acc[i][f][3] + bias4.w;
                        *reinterpret_cast<float4*>((float*)Cout2 + (size_t)m * 96 + (nq - 192)) = vv;
                    }
                } else if (EPI == 1) {
                    float4 add4 = *reinterpret_cast<const float4*>(add + (size_t)m * N + nq);
                    float4 vv;
                    vv.x = acc[i][f][0] + bias4.x + add4.x;
                    vv.y = acc[i][f][1] + bias4.y + add4.y;
                    vv.z = acc[i][f][2] + bias4.z + add4.z;
                    vv.w = acc[i][f][3] + bias4.w + add4.w;
                    *reinterpret_cast<float4*>((float*)Cout + (size_t)m * N + nq) = vv;
                } else { // EPI == 2
                    u16 p0 = f2b(fast_gelu(acc[i][f][0] + bias4.x));
                    u16 p1 = f2b(fast_gelu(acc[i][f][1] + bias4.y));
                    u16 p2 = f2b(fast_gelu(acc[i][f][2] + bias4.z));
                    u16 p3 = f2b(fast_gelu(acc[i][f][3] + bias4.w));
                    uint2 pk = make_uint2((unsigned)p0 | ((unsigned)p1 << 16),
                                          (unsigned)p2 | ((unsigned)p3 << 16));
                    *reinterpret_cast<uint2*>((u16*)Cout + (size_t)m * N + nq) = pk;
                }
            }
        }
    }
}

// ---------------------------------------------------------------------------
// Deformable sampling v3.
// 32-lane group per (b,l,head). Setup: lane j computes corner j's (byte
// offset, weight*aw) -> LDS. Gather: lane j handles channels {2*(j&15),
// 2*(j&15)+1} for the 16 samples of its half (j>>4): dword gathers unpack
// 2 bf16; halves combined via __shfl_xor(16); 16 lanes write packed dwords.
// vbuf: bf16 (B,NH,L,HD); offaw: fp32 (B*L, 96) = [off(72) | aw_logits(24)]
// ---------------------------------------------------------------------------
__global__ __launch_bounds__(256) void deform_kernel(const u16* __restrict__ vbuf,
                                                     const float* __restrict__ offaw,
                                                     u16* __restrict__ dout) {
    __shared__ uint2 cw[8][32];
    int gl = threadIdx.x >> 5;
    int g = blockIdx.x * 8 + gl;
    int j = threadIdx.x & 31;
    int h = g % NH;
    int tmp = g / NH;
    int l = tmp % LL;
    int b = tmp / LL;
    int d = l >> 10, rem = l & 1023, y = rem >> 5, xw = rem & 31;

    const float* oa = offaw + (size_t)(b * LL + l) * 96;
    int p = j >> 3, cor = j & 7;
    int dx = cor & 1, dy = (cor >> 1) & 1, dd = cor >> 2;

    float4 lg = *reinterpret_cast<const float4*>(oa + 72 + h * 4);
    float mx = fmaxf(fmaxf(lg.x, lg.y), fmaxf(lg.z, lg.w));
    float e0 = __expf(lg.x - mx), e1 = __expf(lg.y - mx);
    float e2 = __expf(lg.z - mx), e3 = __expf(lg.w - mx);
    float inv = __builtin_amdgcn_rcpf(e0 + e1 + e2 + e3);
    float ep = (p == 0) ? e0 : (p == 1) ? e1 : (p == 2) ? e2 : e3;
    float awp = ep * inv;

    const float* op = oa + (h * 4 + p) * 3;
    float pd = (d + 0.5f) + op[0] - 0.5f;
    float px = (xw + 0.5f) + op[1] - 0.5f;
    float py = (y + 0.5f) + op[2] - 0.5f;
    float d0f = floorf(pd), x0f = floorf(px), y0f = floorf(py);
    float fd = pd - d0f, fx = px - x0f, fy = py - y0f;
    int di = (int)d0f + dd, yi = (int)y0f + dy, xi = (int)x0f + dx;
    bool inb = (di >= 0) & (di < SS) & (yi >= 0) & (yi < HH) & (xi >= 0) & (xi < WW);
    float wgt = (dd ? fd : 1.f - fd) * (dy ? fy : 1.f - fy) * (dx ? fx : 1.f - fx) * awp;
    wgt = inb ? wgt : 0.f;
    int dic = min(max(di, 0), SS - 1);
    int yic = min(max(yi, 0), HH - 1);
    int xic = min(max(xi, 0), WW - 1);
    int bo = (((dic * HH) + yic) * WW + xic) * (HD * 2);

    cw[gl][j] = make_uint2((unsigned)bo, __float_as_uint(wgt));
    __syncthreads();

    int half = j >> 4, jc = j & 15;
    const char* vbase2 = (const char*)(vbuf + ((size_t)(b * NH + h) * LL) * HD) + 4 * jc;
    const uint4* cw4 = reinterpret_cast<const uint4*>(&cw[gl][half * 16]);
    float a0 = 0.f, a1 = 0.f;
#pragma unroll
    for (int qq = 0; qq < 8; ++qq) {
        uint4 c = cw4[qq];    // uniform per 16-lane subgroup -> broadcast
        unsigned u0 = *reinterpret_cast<const unsigned*>(vbase2 + c.x);
        unsigned u1 = *reinterpret_cast<const unsigned*>(vbase2 + c.z);
        float w0 = __uint_as_float(c.y), w1 = __uint_as_float(c.w);
        a0 += w0 * __uint_as_float(u0 << 16);
        a1 += w0 * __uint_as_float(u0 & 0xffff0000u);
        a0 += w1 * __uint_as_float(u1 << 16);
        a1 += w1 * __uint_as_float(u1 & 0xffff0000u);
    }
    a0 += __shfl_xor(a0, 16);
    a1 += __shfl_xor(a1, 16);
    if (half == 0) {
        unsigned pk = (unsigned)f2b(a0) | ((unsigned)f2b(a1) << 16);
        *reinterpret_cast<unsigned*>(dout + (size_t)(b * LL + l) * CC + h * HD + 2 * jc) = pk;
    }
}

// ---------------------------------------------------------------------------
// LayerNorm over C=192, one wave per row; bf16 output (fc1 input).
// ---------------------------------------------------------------------------
__global__ __launch_bounds__(256) void layernorm_kernel(const float* __restrict__ hin,
                                                        const float* __restrict__ g2,
                                                        const float* __restrict__ b2,
                                                        u16* __restrict__ lnout) {
    int row = blockIdx.x * 4 + (threadIdx.x >> 6);
    int lane = threadIdx.x & 63;
    const float* hr = hin + (size_t)row * CC;
    float v0 = hr[lane], v1 = hr[lane + 64], v2 = hr[lane + 128];
    float s = v0 + v1 + v2;
    float sq = v0 * v0 + v1 * v1 + v2 * v2;
#pragma unroll
    for (int o = 32; o > 0; o >>= 1) {
        s += __shfl_xor(s, o);
        sq += __shfl_xor(sq, o);
    }
    float m = s * (1.0f / CC);
    float var = sq * (1.0f / CC) - m * m;
    float r = rsqrtf(var + 1e-5f);
    u16* lo = lnout + (size_t)row * CC;
    lo[lane]       = f2b((v0 - m) * r * g2[lane]       + b2[lane]);
    lo[lane + 64]  = f2b((v1 - m) * r * g2[lane + 64]  + b2[lane + 64]);
    lo[lane + 128] = f2b((v2 - m) * r * g2[lane + 128] + b2[lane + 128]);
}

// ---------------------------------------------------------------------------
extern "C" void kernel_launch(void* const* d_in, const int* in_sizes, int n_in,
                              void* d_out, int out_size, void* d_ws, size_t ws_size,
                              hipStream_t stream) {
    const float* x    = (const float*)d_in[0];
    const float* Wv   = (const float*)d_in[2];
    const float* bv   = (const float*)d_in[3];
    const float* Woff = (const float*)d_in[4];
    const float* boff = (const float*)d_in[5];
    const float* Waw  = (const float*)d_in[6];
    const float* baw  = (const float*)d_in[7];
    const float* Wout = (const float*)d_in[8];
    const float* bout = (const float*)d_in[9];
    const float* g2   = (const float*)d_in[10];
    const float* b2   = (const float*)d_in[11];
    const float* W1   = (const float*)d_in[12];
    const float* b1   = (const float*)d_in[13];
    const float* W2   = (const float*)d_in[14];
    const float* b2m  = (const float*)d_in[15];

    char* wsb = (char*)d_ws;
    u16*   xp    = (u16*)(wsb + 0);              // [0, 12.6M)
    u16*   vbuf  = (u16*)(wsb + 12582912);       // [12.6M, 25.2M)
    float* offaw = (float*)(wsb + 25165824);     // [25.2M, 37.8M)
    u16*   dbuf  = (u16*)(wsb + 0);              // reuses xp (dead after proj gemm)
    u16*   hid   = (u16*)(wsb + 12582912);       // reuses vbuf+offaw (dead after deform)
    float* hbuf  = (float*)(wsb + 66060288);
    u16*   ln    = (u16*)(wsb + 92274688);
    u16*   wcatT = (u16*)(wsb + 105906176);
    u16*   woutT = wcatT + NPROJ * CC;
    u16*   w1T   = woutT + CC * CC;
    u16*   w2T   = w1T + HID * CC;
    float* bcat  = (float*)(w2T + CC * HID);
    float* out   = (float*)d_out;

    int wtot = NPROJ * CC + CC * CC + HID * CC + CC * HID + NPROJ;
    build_weights<<<(wtot + 255) / 256, 256, 0, stream>>>(
        Wv, Woff, Waw, Wout, W1, W2, bv, boff, baw, wcatT, woutT, w1T, w2T, bcat);
    transpose_in<<<dim3(LL / 32, CC / 32, BB), dim3(32, 8), 0, stream>>>(x, xp);
    gemm_mfma<0, 3><<<dim3(3, MTOK / 128), 256, 0, stream>>>(
        xp, wcatT, bcat, nullptr, vbuf, offaw, MTOK, NPROJ, CC);
    deform_kernel<<<(BB * LL * NH) / 8, 256, 0, stream>>>(vbuf, offaw, dbuf);
    gemm_mfma<1, 3><<<dim3(2, MTOK / 128), 256, 0, stream>>>(
        dbuf, woutT, bout, x /* shortcut view */, hbuf, nullptr, MTOK, CC, CC);
    layernorm_kernel<<<MTOK / 4, 256, 0, stream>>>(hbuf, g2, b2, ln);
    gemm_mfma<2, 6><<<dim3(4, MTOK / 128), 256, 0, stream>>>(
        ln, w1T, b1, nullptr, hid, nullptr, MTOK, HID, CC);
    gemm_mfma<3, 3><<<dim3(2, MTOK / 128), 256, 0, stream>>>(
        hid, w2T, b2m, hbuf, out, nullptr, MTOK, CC, HID);
}

// Round 10
// 221.447 us; speedup vs baseline: 3.8804x; 1.0296x over previous
//
#include <hip/hip_runtime.h>
#include <hip/hip_bf16.h>
#include <math.h>

// Problem constants
#define BB 2
#define CC 192
#define SS 16
#define HH 32
#define WW 32
#define NH 6
#define PP 4
#define HD 32
#define HID 768
#define LL (SS * HH * WW)        // 16384
#define MTOK (BB * LL)           // 32768 tokens
#define NPROJ 288                // 192 (value) + 72 (off) + 24 (aw->weights)

typedef unsigned short u16;
typedef u16 u16x8 __attribute__((ext_vector_type(8)));
typedef __bf16 bf16x8 __attribute__((ext_vector_type(8)));
typedef float f32x4 __attribute__((ext_vector_type(4)));

static __device__ __forceinline__ u16 f2b(float f) {
    __hip_bfloat16 h = __float2bfloat16(f);
    return *reinterpret_cast<u16*>(&h);
}

// fast GELU: v * sigmoid(1.5957691(v + 0.044715 v^3)); |err| ~1e-3 << bf16 ulp here
static __device__ __forceinline__ float fast_gelu(float v) {
    float z = 1.5957691216057308f * (v + 0.044715f * v * v * v);
    return v * __builtin_amdgcn_rcpf(1.0f + __expf(-z));
}

// ---------------------------------------------------------------------------
// Build all bf16 transposed weights (N x K layout) + concatenated bias (fp32)
// ---------------------------------------------------------------------------
__global__ void build_weights(const float* __restrict__ Wv, const float* __restrict__ Woff,
                              const float* __restrict__ Waw, const float* __restrict__ Wout,
                              const float* __restrict__ W1, const float* __restrict__ W2,
                              const float* __restrict__ bv, const float* __restrict__ boff,
                              const float* __restrict__ baw,
                              u16* __restrict__ wcatT, u16* __restrict__ woutT,
                              u16* __restrict__ w1T, u16* __restrict__ w2T,
                              float* __restrict__ bcat) {
    int i = blockIdx.x * 256 + threadIdx.x;
    if (i < NPROJ * CC) {                       // wcatT[n][k] = Wcat[k][n]
        int n = i / CC, k = i % CC;
        float v = (n < 192) ? Wv[k * 192 + n]
                : (n < 264) ? Woff[k * 72 + (n - 192)]
                            : Waw[k * 24 + (n - 264)];
        wcatT[i] = f2b(v);
        return;
    }
    i -= NPROJ * CC;
    if (i < CC * CC) {
        int n = i / CC, k = i % CC;
        woutT[i] = f2b(Wout[k * CC + n]);
        return;
    }
    i -= CC * CC;
    if (i < HID * CC) {
        int n = i / CC, k = i % CC;
        w1T[i] = f2b(W1[k * HID + n]);
        return;
    }
    i -= HID * CC;
    if (i < CC * HID) {
        int n = i / HID, k = i % HID;
        w2T[i] = f2b(W2[k * CC + n]);
        return;
    }
    i -= CC * HID;
    if (i < NPROJ) {
        float v = (i < 192) ? bv[i] : (i < 264) ? boff[i - 192] : baw[i - 264];
        bcat[i] = v;
    }
}

// ---------------------------------------------------------------------------
// x (B, C, L) channel-major  ->  xp (B, L, C) token-major bf16
// ---------------------------------------------------------------------------
__global__ void transpose_in(const float* __restrict__ x, u16* __restrict__ xp) {
    __shared__ float s[32][33];
    int b = blockIdx.z;
    int c0 = blockIdx.y * 32;
    int l0 = blockIdx.x * 32;
    int tx = threadIdx.x, ty = threadIdx.y;
#pragma unroll
    for (int r = 0; r < 32; r += 8)
        s[ty + r][tx] = x[((size_t)b * CC + c0 + ty + r) * LL + l0 + tx];
    __syncthreads();
#pragma unroll
    for (int r = 0; r < 32; r += 8)
        xp[((size_t)b * LL + l0 + ty + r) * CC + c0 + tx] = f2b(s[tx][ty + r]);
}

// ---------------------------------------------------------------------------
// MFMA bf16 GEMM: C(MxN) = A(MxK) @ Bt(NxK)^T + bias.  BM=128, BN=32*NF.
// 256 threads = 4 waves (2x2), wave tile 64 x (16*NF).
// Double-buffered LDS, ONE barrier per K-step (reg prefetch of k+1).
// EPI 0/1/2/4 operands SWAPPED (mfma(b,a)): n in acc regs, m on lanes.
// EPI: 0 = split: n<192 -> vbuf bf16 (B,NH,L,HD); off raw fp32; aw SOFTMAXed
//      2 = bf16 out fast_gelu(acc+bias) (fc1), token-major
//      3 = fp32 out + bias + add, CHANNEL-MAJOR (B,C,L) (fc2+residual), unswapped
//      4 = wout + shortcut-add + LayerNorm fused (NF=6): writes h fp32 AND
//          ln bf16 (stats via shfl_xor over q + LDS exchange across wn pair)
// ---------------------------------------------------------------------------
template<int EPI, int NF>
__global__ __launch_bounds__(256, 2) void gemm_mfma(const u16* __restrict__ A,
                                                    const u16* __restrict__ Bt,
                                                    const float* __restrict__ bias,
                                                    const float* __restrict__ add,
                                                    void* __restrict__ Cout,
                                                    void* __restrict__ Cout2,
                                                    const float* __restrict__ g2p,
                                                    const float* __restrict__ b2p,
                                                    int M, int N, int K) {
    constexpr int BN = NF * 32;
    constexpr int NB = (BN * 4 + 255) / 256;   // B-load slots per thread
    __shared__ u16 As[2][128][40];
    __shared__ u16 Bs[2][BN][40];
    __shared__ float redS[2][2][64];
    __shared__ float redQ[2][2][64];
    int t = threadIdx.x;
    int m0 = blockIdx.y * 128;
    int n0 = blockIdx.x * BN;
    int w = t >> 6, lane = t & 63;
    int wm = w >> 1, wn = w & 1;
    int lrow = lane & 15, q = lane >> 4;
    int lk8 = q * 8;

    f32x4 acc[4][NF];
#pragma unroll
    for (int i = 0; i < 4; ++i)
#pragma unroll
        for (int f = 0; f < NF; ++f)
#pragma unroll
            for (int r = 0; r < 4; ++r) acc[i][f][r] = 0.f;

    int arow = t >> 2, aseg = (t & 3) * 8;
    const u16* Arow0 = A + (size_t)(m0 + arow) * K + aseg;
    const u16* Arow1 = A + (size_t)(m0 + arow + 64) * K + aseg;

    u16x8 av0, av1, bvr[NB];
    av0 = *reinterpret_cast<const u16x8*>(Arow0);
    av1 = *reinterpret_cast<const u16x8*>(Arow1);
#pragma unroll
    for (int u2 = 0; u2 < NB; ++u2) {
        int ii = t + u2 * 256;
        if (ii < BN * 4) {
            int br = ii >> 2, bseg = (ii & 3) * 8;
            bvr[u2] = *reinterpret_cast<const u16x8*>(Bt + (size_t)(n0 + br) * K + bseg);
        }
    }
    *reinterpret_cast<u16x8*>(&As[0][arow][aseg]) = av0;
    *reinterpret_cast<u16x8*>(&As[0][arow + 64][aseg]) = av1;
#pragma unroll
    for (int u2 = 0; u2 < NB; ++u2) {
        int ii = t + u2 * 256;
        if (ii < BN * 4) {
            int br = ii >> 2, bseg = (ii & 3) * 8;
            *reinterpret_cast<u16x8*>(&Bs[0][br][bseg]) = bvr[u2];
        }
    }
    __syncthreads();

    int NT = K >> 5;
    int cur = 0;
    for (int ti = 0; ti < NT - 1; ++ti) {
        int k1 = (ti + 1) << 5;
        av0 = *reinterpret_cast<const u16x8*>(Arow0 + k1);
        av1 = *reinterpret_cast<const u16x8*>(Arow1 + k1);
#pragma unroll
        for (int u2 = 0; u2 < NB; ++u2) {
            int ii = t + u2 * 256;
            if (ii < BN * 4) {
                int br = ii >> 2, bseg = (ii & 3) * 8;
                bvr[u2] = *reinterpret_cast<const u16x8*>(Bt + (size_t)(n0 + br) * K + k1 + bseg);
            }
        }
        {
            bf16x8 af[4], bfr[NF];
#pragma unroll
            for (int i = 0; i < 4; ++i)
                af[i] = *reinterpret_cast<const bf16x8*>(&As[cur][wm * 64 + i * 16 + lrow][lk8]);
#pragma unroll
            for (int f = 0; f < NF; ++f)
                bfr[f] = *reinterpret_cast<const bf16x8*>(&Bs[cur][wn * (16 * NF) + f * 16 + lrow][lk8]);
#pragma unroll
            for (int i = 0; i < 4; ++i)
#pragma unroll
                for (int f = 0; f < NF; ++f) {
                    if (EPI == 3)
                        acc[i][f] = __builtin_amdgcn_mfma_f32_16x16x32_bf16(af[i], bfr[f], acc[i][f], 0, 0, 0);
                    else
                        acc[i][f] = __builtin_amdgcn_mfma_f32_16x16x32_bf16(bfr[f], af[i], acc[i][f], 0, 0, 0);
                }
        }
        *reinterpret_cast<u16x8*>(&As[cur ^ 1][arow][aseg]) = av0;
        *reinterpret_cast<u16x8*>(&As[cur ^ 1][arow + 64][aseg]) = av1;
#pragma unroll
        for (int u2 = 0; u2 < NB; ++u2) {
            int ii = t + u2 * 256;
            if (ii < BN * 4) {
                int br = ii >> 2, bseg = (ii & 3) * 8;
                *reinterpret_cast<u16x8*>(&Bs[cur ^ 1][br][bseg]) = bvr[u2];
            }
        }
        __syncthreads();
        cur ^= 1;
    }
    {
        bf16x8 af[4], bfr[NF];
#pragma unroll
        for (int i = 0; i < 4; ++i)
            af[i] = *reinterpret_cast<const bf16x8*>(&As[cur][wm * 64 + i * 16 + lrow][lk8]);
#pragma unroll
        for (int f = 0; f < NF; ++f)
            bfr[f] = *reinterpret_cast<const bf16x8*>(&Bs[cur][wn * (16 * NF) + f * 16 + lrow][lk8]);
#pragma unroll
        for (int i = 0; i < 4; ++i)
#pragma unroll
            for (int f = 0; f < NF; ++f) {
                if (EPI == 3)
                    acc[i][f] = __builtin_amdgcn_mfma_f32_16x16x32_bf16(af[i], bfr[f], acc[i][f], 0, 0, 0);
                else
                    acc[i][f] = __builtin_amdgcn_mfma_f32_16x16x32_bf16(bfr[f], af[i], acc[i][f], 0, 0, 0);
            }
    }

    if (EPI == 3) {
        // m in regs: channel-major float4 along l
#pragma unroll
        for (int i = 0; i < 4; ++i) {
#pragma unroll
            for (int f = 0; f < NF; ++f) {
                int n = n0 + wn * (16 * NF) + f * 16 + lrow;
                float bvn = bias[n];
                int mb = m0 + wm * 64 + i * 16 + q * 4;
                float4 vv;
#pragma unroll
                for (int r = 0; r < 4; ++r)
                    ((float*)&vv)[r] = acc[i][f][r] + bvn + add[(size_t)(mb + r) * N + n];
                int b = mb >> 14, l = mb & (LL - 1);
                *reinterpret_cast<float4*>((float*)Cout + ((size_t)b * CC + n) * LL + l) = vv;
            }
        }
    } else if (EPI == 4) {
        // wout + shortcut + LayerNorm. v -> Cout (h fp32); ln -> Cout2 (bf16)
        float s_[4], sq_[4];
#pragma unroll
        for (int i = 0; i < 4; ++i) {
            int m = m0 + wm * 64 + i * 16 + lrow;
            float s = 0.f, sq = 0.f;
#pragma unroll
            for (int f = 0; f < NF; ++f) {
                int nq = n0 + wn * (16 * NF) + f * 16 + q * 4;
                float4 bias4 = *reinterpret_cast<const float4*>(bias + nq);
                float4 add4 = *reinterpret_cast<const float4*>(add + (size_t)m * N + nq);
                float4 vv;
#pragma unroll
                for (int r = 0; r < 4; ++r) {
                    float v = acc[i][f][r] + ((const float*)&bias4)[r] + ((const float*)&add4)[r];
                    acc[i][f][r] = v;
                    s += v;
                    sq += v * v;
                    ((float*)&vv)[r] = v;
                }
                *reinterpret_cast<float4*>((float*)Cout + (size_t)m * N + nq) = vv;
            }
            s += __shfl_xor(s, 16);  s += __shfl_xor(s, 32);
            sq += __shfl_xor(sq, 16); sq += __shfl_xor(sq, 32);
            s_[i] = s; sq_[i] = sq;
        }
        float wsel = (q == 0) ? s_[0] : (q == 1) ? s_[1] : (q == 2) ? s_[2] : s_[3];
        float wqel = (q == 0) ? sq_[0] : (q == 1) ? sq_[1] : (q == 2) ? sq_[2] : sq_[3];
        redS[wm][wn][q * 16 + lrow] = wsel;
        redQ[wm][wn][q * 16 + lrow] = wqel;
        __syncthreads();
#pragma unroll
        for (int i = 0; i < 4; ++i) {
            int m = m0 + wm * 64 + i * 16 + lrow;
            float ts = s_[i] + redS[wm][wn ^ 1][i * 16 + lrow];
            float tq = sq_[i] + redQ[wm][wn ^ 1][i * 16 + lrow];
            float mean = ts * (1.0f / CC);
            float var = tq * (1.0f / CC) - mean * mean;
            float rr = rsqrtf(var + 1e-5f);
#pragma unroll
            for (int f = 0; f < NF; ++f) {
                int nq = n0 + wn * (16 * NF) + f * 16 + q * 4;
                float4 gg = *reinterpret_cast<const float4*>(g2p + nq);
                float4 bb = *reinterpret_cast<const float4*>(b2p + nq);
                u16 p0 = f2b((acc[i][f][0] - mean) * rr * gg.x + bb.x);
                u16 p1 = f2b((acc[i][f][1] - mean) * rr * gg.y + bb.y);
                u16 p2 = f2b((acc[i][f][2] - mean) * rr * gg.z + bb.z);
                u16 p3 = f2b((acc[i][f][3] - mean) * rr * gg.w + bb.w);
                uint2 pk = make_uint2((unsigned)p0 | ((unsigned)p1 << 16),
                                      (unsigned)p2 | ((unsigned)p3 << 16));
                *reinterpret_cast<uint2*>((u16*)Cout2 + (size_t)m * CC + nq) = pk;
            }
        }
    } else {
        // swapped: n in regs (4 consecutive), m on lanes
#pragma unroll
        for (int i = 0; i < 4; ++i) {
            int m = m0 + wm * 64 + i * 16 + lrow;
#pragma unroll
            for (int f = 0; f < NF; ++f) {
                int nq = n0 + wn * (16 * NF) + f * 16 + q * 4;
                float4 bias4 = *reinterpret_cast<const float4*>(bias + nq);
                if (EPI == 0) {
                    if (nq < 192) {
                        int h = nq >> 5, hd = nq & 31;
                        int b = m >> 14, l = m & (LL - 1);
                        u16 p0 = f2b(acc[i][f][0] + bias4.x);
                        u16 p1 = f2b(acc[i][f][1] + bias4.y);
                        u16 p2 = f2b(acc[i][f][2] + bias4.z);
                        u16 p3 = f2b(acc[i][f][3] + bias4.w);
                        uint2 pk = make_uint2((unsigned)p0 | ((unsigned)p1 << 16),
                                              (unsigned)p2 | ((unsigned)p3 << 16));
                        *reinterpret_cast<uint2*>(
                            (u16*)Cout + (((size_t)b * NH + h) * LL + l) * HD + hd) = pk;
                    } else if (nq < 264) {
                        float4 vv;
                        vv.x = acc[i][f][0] + bias4.x;
                        vv.y = acc[i][f][1] + bias4.y;
                        vv.z = acc[i][f][2] + bias4.z;
                        vv.w = acc[i][f][3] + bias4.w;
                        *reinterpret_cast<float4*>((float*)Cout2 + (size_t)m * 96 + (nq - 192)) = vv;
                    } else {
                        // attention-weight softmax in-register (4 logits = 1 head)
                        float l0 = acc[i][f][0] + bias4.x;
                        float l1 = acc[i][f][1] + bias4.y;
                        float l2 = acc[i][f][2] + bias4.z;
                        float l3 = acc[i][f][3] + bias4.w;
                        float mx = fmaxf(fmaxf(l0, l1), fmaxf(l2, l3));
                        float e0 = __expf(l0 - mx), e1 = __expf(l1 - mx);
                        float e2 = __expf(l2 - mx), e3 = __expf(l3 - mx);
                        float inv = __builtin_amdgcn_rcpf(e0 + e1 + e2 + e3);
                        float4 vv;
                        vv.x = e0 * inv; vv.y = e1 * inv; vv.z = e2 * inv; vv.w = e3 * inv;
                        *reinterpret_cast<float4*>((float*)Cout2 + (size_t)m * 96 + (nq - 192)) = vv;
                    }
                } else { // EPI == 2
                    u16 p0 = f2b(fast_gelu(acc[i][f][0] + bias4.x));
                    u16 p1 = f2b(fast_gelu(acc[i][f][1] + bias4.y));
                    u16 p2 = f2b(fast_gelu(acc[i][f][2] + bias4.z));
                    u16 p3 = f2b(fast_gelu(acc[i][f][3] + bias4.w));
                    uint2 pk = make_uint2((unsigned)p0 | ((unsigned)p1 << 16),
                                          (unsigned)p2 | ((unsigned)p3 << 16));
                    *reinterpret_cast<uint2*>((u16*)Cout + (size_t)m * N + nq) = pk;
                }
            }
        }
    }
}

// ---------------------------------------------------------------------------
// Deformable sampling v4 (softmax pre-applied in proj epilogue).
// 32-lane group per (b,l,head). Lane j computes corner j's (byte offset,
// weight) -> LDS; after barrier lanes gather dwords (2 bf16 channels) for 16
// samples each (half split), combine via shfl_xor(16), packed dword writes.
// vbuf: bf16 (B,NH,L,HD); offaw: fp32 (B*L, 96) = [off(72) | aw WEIGHTS(24)]
// ---------------------------------------------------------------------------
__global__ __launch_bounds__(256) void deform_kernel(const u16* __restrict__ vbuf,
                                                     const float* __restrict__ offaw,
                                                     u16* __restrict__ dout) {
    __shared__ uint2 cw[8][32];
    int gl = threadIdx.x >> 5;
    int g = blockIdx.x * 8 + gl;
    int j = threadIdx.x & 31;
    int h = g % NH;
    int tmp = g / NH;
    int l = tmp % LL;
    int b = tmp / LL;
    int d = l >> 10, rem = l & 1023, y = rem >> 5, xw = rem & 31;

    const float* oa = offaw + (size_t)(b * LL + l) * 96;
    int p = j >> 3, cor = j & 7;
    int dx = cor & 1, dy = (cor >> 1) & 1, dd = cor >> 2;

    float awp = oa[72 + h * 4 + p];   // softmax already applied

    const float* op = oa + (h * 4 + p) * 3;
    float pd = (d + 0.5f) + op[0] - 0.5f;
    float px = (xw + 0.5f) + op[1] - 0.5f;
    float py = (y + 0.5f) + op[2] - 0.5f;
    float d0f = floorf(pd), x0f = floorf(px), y0f = floorf(py);
    float fd = pd - d0f, fx = px - x0f, fy = py - y0f;
    int di = (int)d0f + dd, yi = (int)y0f + dy, xi = (int)x0f + dx;
    bool inb = (di >= 0) & (di < SS) & (yi >= 0) & (yi < HH) & (xi >= 0) & (xi < WW);
    float wgt = (dd ? fd : 1.f - fd) * (dy ? fy : 1.f - fy) * (dx ? fx : 1.f - fx) * awp;
    wgt = inb ? wgt : 0.f;
    int dic = min(max(di, 0), SS - 1);
    int yic = min(max(yi, 0), HH - 1);
    int xic = min(max(xi, 0), WW - 1);
    int bo = (((dic * HH) + yic) * WW + xic) * (HD * 2);

    cw[gl][j] = make_uint2((unsigned)bo, __float_as_uint(wgt));
    __syncthreads();

    int half = j >> 4, jc = j & 15;
    const char* vbase2 = (const char*)(vbuf + ((size_t)(b * NH + h) * LL) * HD) + 4 * jc;
    const uint4* cw4 = reinterpret_cast<const uint4*>(&cw[gl][half * 16]);
    float a0 = 0.f, a1 = 0.f;
#pragma unroll
    for (int qq = 0; qq < 8; ++qq) {
        uint4 c = cw4[qq];    // uniform per 16-lane subgroup -> broadcast
        unsigned u0 = *reinterpret_cast<const unsigned*>(vbase2 + c.x);
        unsigned u1 = *reinterpret_cast<const unsigned*>(vbase2 + c.z);
        float w0 = __uint_as_float(c.y), w1 = __uint_as_float(c.w);
        a0 += w0 * __uint_as_float(u0 << 16);
        a1 += w0 * __uint_as_float(u0 & 0xffff0000u);
        a0 += w1 * __uint_as_float(u1 << 16);
        a1 += w1 * __uint_as_float(u1 & 0xffff0000u);
    }
    a0 += __shfl_xor(a0, 16);
    a1 += __shfl_xor(a1, 16);
    if (half == 0) {
        unsigned pk = (unsigned)f2b(a0) | ((unsigned)f2b(a1) << 16);
        *reinterpret_cast<unsigned*>(dout + (size_t)(b * LL + l) * CC + h * HD + 2 * jc) = pk;
    }
}

// ---------------------------------------------------------------------------
extern "C" void kernel_launch(void* const* d_in, const int* in_sizes, int n_in,
                              void* d_out, int out_size, void* d_ws, size_t ws_size,
                              hipStream_t stream) {
    const float* x    = (const float*)d_in[0];
    const float* Wv   = (const float*)d_in[2];
    const float* bv   = (const float*)d_in[3];
    const float* Woff = (const float*)d_in[4];
    const float* boff = (const float*)d_in[5];
    const float* Waw  = (const float*)d_in[6];
    const float* baw  = (const float*)d_in[7];
    const float* Wout = (const float*)d_in[8];
    const float* bout = (const float*)d_in[9];
    const float* g2   = (const float*)d_in[10];
    const float* b2   = (const float*)d_in[11];
    const float* W1   = (const float*)d_in[12];
    const float* b1   = (const float*)d_in[13];
    const float* W2   = (const float*)d_in[14];
    const float* b2m  = (const float*)d_in[15];

    char* wsb = (char*)d_ws;
    u16*   xp    = (u16*)(wsb + 0);              // [0, 12.6M)
    u16*   vbuf  = (u16*)(wsb + 12582912);       // [12.6M, 25.2M)
    float* offaw = (float*)(wsb + 25165824);     // [25.2M, 37.8M)
    u16*   dbuf  = (u16*)(wsb + 0);              // reuses xp (dead after proj gemm)
    u16*   hid   = (u16*)(wsb + 12582912);       // reuses vbuf+offaw (dead after deform)
    float* hbuf  = (float*)(wsb + 66060288);
    u16*   ln    = (u16*)(wsb + 92274688);
    u16*   wcatT = (u16*)(wsb + 105906176);
    u16*   woutT = wcatT + NPROJ * CC;
    u16*   w1T   = woutT + CC * CC;
    u16*   w2T   = w1T + HID * CC;
    float* bcat  = (float*)(w2T + CC * HID);
    float* out   = (float*)d_out;

    int wtot = NPROJ * CC + CC * CC + HID * CC + CC * HID + NPROJ;
    build_weights<<<(wtot + 255) / 256, 256, 0, stream>>>(
        Wv, Woff, Waw, Wout, W1, W2, bv, boff, baw, wcatT, woutT, w1T, w2T, bcat);
    transpose_in<<<dim3(LL / 32, CC / 32, BB), dim3(32, 8), 0, stream>>>(x, xp);
    gemm_mfma<0, 3><<<dim3(3, MTOK / 128), 256, 0, stream>>>(
        xp, wcatT, bcat, nullptr, vbuf, offaw, nullptr, nullptr, MTOK, NPROJ, CC);
    deform_kernel<<<(BB * LL * NH) / 8, 256, 0, stream>>>(vbuf, offaw, dbuf);
    gemm_mfma<4, 6><<<dim3(1, MTOK / 128), 256, 0, stream>>>(
        dbuf, woutT, bout, x /* shortcut view */, hbuf, ln, g2, b2, MTOK, CC, CC);
    gemm_mfma<2, 6><<<dim3(4, MTOK / 128), 256, 0, stream>>>(
        ln, w1T, b1, nullptr, hid, nullptr, nullptr, nullptr, MTOK, HID, CC);
    gemm_mfma<3, 3><<<dim3(2, MTOK / 128), 256, 0, stream>>>(
        hid, w2T, b2m, hbuf, out, nullptr, nullptr, nullptr, MTOK, CC, HID);
}